// Round 7
// baseline (585.036 us; speedup 1.0000x reference)
//
#include <hip/hip_runtime.h>
#include <hip/hip_bf16.h>

// FPGNN forward for MI355X. Round 19: R5 structure (plain launches, verbatim
// bodies) with dispatch-count cuts by SAFE means after the cooperative mega
// failed (R6 absmax 0.523 == max|ref| => launch silently failed/skipped):
//  (1) fb1 tiles ride in the att2t launch (+16 blocks, stream-order dep).
//  (2) fb2 tiles ride in the gat2 launch (+16 blocks).
//  (3) fb3/fb4/fb5/ffn2 fused into ONE 16-block persistent kernel with a
//      device-scope atomicAdd+threadfence barrier (16 blocks trivially
//      co-resident; counter zeroed by prep each launch).
// Dispatches: 10 -> 5.
// Shapes: B=512, N=128, F_IN=133, NHEADS=8, NHID=64, HID=512, FP_DIM=1489, TASKS=12

#define ALPHA_LK 0.2f
#define LOG2E 1.44269504f
#define KP1 192   // F_IN=133 padded to 3*64
#define KPF 1536  // FP_DIM=1489 padded to 24*64
#define MINF_BF16 0xFF80u

typedef unsigned short ushort_t;
typedef __attribute__((ext_vector_type(8))) short bfrag;   // 8 x bf16 (4 VGPRs)
typedef __attribute__((ext_vector_type(4))) float ffrag;   // 4 x f32 acc

__device__ __forceinline__ float b2f(ushort_t u) {
  return __uint_as_float(((unsigned)u) << 16);
}
__device__ __forceinline__ ushort_t f2b(float f) {
  unsigned u = __float_as_uint(f);
  unsigned r = (u + 0x7fffu + ((u >> 16) & 1u)) >> 16;  // RNE
  return (ushort_t)r;
}
__device__ __forceinline__ unsigned cvt_pk(float lo, float hi) {
  unsigned r;
  asm("v_cvt_pk_bf16_f32 %0, %1, %2" : "=v"(r) : "v"(lo), "v"(hi));
  return r;
}
__device__ __forceinline__ float frcp(float x) {
  float r;
  asm("v_rcp_f32 %0, %1" : "=v"(r) : "v"(x));
  return r;
}
__device__ __forceinline__ float fexp2(float x) {
#if __has_builtin(__builtin_amdgcn_exp2f)
  return __builtin_amdgcn_exp2f(x);
#else
  return exp2f(x);
#endif
}
__device__ __forceinline__ float elu1(float v) {
  return v > 0.f ? v : __expf(v) - 1.f;
}
__device__ __forceinline__ void gll16(const void* g, void* l) {
  __builtin_amdgcn_global_load_lds(
      (const __attribute__((address_space(1))) unsigned int*)(unsigned long long)g,
      (__attribute__((address_space(3))) unsigned int*)(unsigned long long)l,
      16, 0, 0);
}

// ---------------------------------------------------------------------------
struct MP {
  const float *h; const int *adj; const float *edge; const float *fp;
  const float *Whd, *a1h, *a2h, *aeh;
  const float *W_out, *a1o, *a2o, *aeo;
  const float *fc1_w, *fc1_b, *fc2_w, *fc2_b;
  const float *q_b, *v_b, *q_w, *v_w, *o_w, *o_b;
  const float *ffn1_w, *ffn1_b, *ffn2_w, *ffn2_b;
  ushort_t *hb, *em, *W2t, *wh12, *fpb, *fc1t, *Wot, *fc2t, *qwt, *vwt, *owt, *f1t;
  ushort_t *xb, *awg; float *sinv;
  ushort_t *gatb, *fb1, *fb2, *fb3, *fb4, *fb5;
  float *wa1, *wa2, *qvb; float *out;
  unsigned *cnt;
  int C;
};

struct LdsGat1 {
  union { struct { ushort_t As[128][64]; ushort_t Bs[64][64]; } g;
          ushort_t WS[64][136]; } u;
  float ss1[128], ss2[128];
  ushort_t wh12s[2][192];
};
struct LdsGat2 {
  union { struct { ushort_t As[128][64]; ushort_t Bs[128][64]; } g;
          ushort_t WS[128][136]; } u;
  float ps[4][64];
};
struct LdsAtt { float t1s[128], t2s[128], was1[512], was2[512]; };
struct LdsTail { ushort_t As[128][64]; ushort_t Bs[128][64]; };

// device-scope barrier for a small co-resident grid (16 blocks).
__device__ __forceinline__ void tbar(unsigned* cnt, unsigned target) {
  __syncthreads();
  __threadfence();
  if (threadIdx.x == 0) {
    atomicAdd(cnt, 1u);
    while (atomicAdd(cnt, 0u) < target) __builtin_amdgcn_s_sleep(1);
  }
  __syncthreads();
  __threadfence();
}

// ---------------------------------------------------------------------------
// prep: all preamble work, segmented by block id (23786 total).
__device__ void prep_body(int bid, const MP& P) {
  const int t = threadIdx.x;
  if (bid < 8) {  // wh12
    int hh = bid;
    if (t < 192) {
      float s1 = 0.f, s2 = 0.f;
      if (t < 133) {
        const float* wr = P.Whd + (size_t)(hh * 133 + t) * 64;
        const float* a1r = P.a1h + hh * 64;
        const float* a2r = P.a2h + hh * 64;
#pragma unroll 8
        for (int d = 0; d < 64; ++d) {
          float wv = wr[d];
          s1 += wv * a1r[d];
          s2 += wv * a2r[d];
        }
      }
      P.wh12[hh * 384 + t] = f2b(s1);
      P.wh12[hh * 384 + 192 + t] = f2b(s2);
    }
    return;
  }
  bid -= 8;
  if (bid < 128) {  // wa12
    int wv = t >> 6, lane = t & 63;
    int k = bid * 4 + wv;
    const float* wr = P.W_out + (size_t)k * 512;
    float p1 = 0.f, p2 = 0.f;
#pragma unroll
    for (int i = 0; i < 8; ++i) {
      float v = wr[lane + i * 64];
      p1 += v * P.a1o[lane + i * 64];
      p2 += v * P.a2o[lane + i * 64];
    }
#pragma unroll
    for (int off = 32; off; off >>= 1) {
      p1 += __shfl_down(p1, off);
      p2 += __shfl_down(p2, off);
    }
    if (lane == 0) { P.wa1[k] = p1; P.wa2[k] = p2; }
    return;
  }
  bid -= 128;
  if (bid < 2) {  // qvb + barrier-counter zero
    int o = bid * 256 + t;
    P.qvb[o] = P.q_b[o] + P.v_b[o];
    if (bid == 0 && t == 0) P.cnt[0] = 0u;
    return;
  }
  bid -= 2;
  if (bid < 96) {  // W2t
    int o = bid * 256 + t;
    if (o < 512 * 48) {
      int col = o / 48, c4 = (o - col * 48) * 4;
      int hh = col >> 6, d = col & 63;
      ushort4 v;
      v.x = (c4 + 0 < 133) ? f2b(P.Whd[(hh * 133 + c4 + 0) * 64 + d]) : (ushort_t)0;
      v.y = (c4 + 1 < 133) ? f2b(P.Whd[(hh * 133 + c4 + 1) * 64 + d]) : (ushort_t)0;
      v.z = (c4 + 2 < 133) ? f2b(P.Whd[(hh * 133 + c4 + 2) * 64 + d]) : (ushort_t)0;
      v.w = (c4 + 3 < 133) ? f2b(P.Whd[(hh * 133 + c4 + 3) * 64 + d]) : (ushort_t)0;
      *(ushort4*)&P.W2t[(size_t)col * KP1 + c4] = v;
    }
    return;
  }
  bid -= 96;
  if (bid < 768) {  // fpb
    int o = bid * 256 + t;
    int row = o / 384, c4 = (o - row * 384) * 4;
    const float* fr = P.fp + (size_t)row * 1489;
    ushort4 v;
    v.x = (c4 + 0 < 1489) ? f2b(fr[c4 + 0]) : (ushort_t)0;
    v.y = (c4 + 1 < 1489) ? f2b(fr[c4 + 1]) : (ushort_t)0;
    v.z = (c4 + 2 < 1489) ? f2b(fr[c4 + 2]) : (ushort_t)0;
    v.w = (c4 + 3 < 1489) ? f2b(fr[c4 + 3]) : (ushort_t)0;
    *(ushort4*)&P.fpb[(size_t)row * KPF + c4] = v;
    return;
  }
  bid -= 768;
  if (bid < 768) {  // fc1t (transpose K=1489 N=512 Kpad=1536)
    int o = bid * 256 + t;
    int col = o / 384, k4 = (o - col * 384) * 4;
    ushort4 v;
    v.x = (k4 + 0 < 1489) ? f2b(P.fc1_w[(size_t)(k4 + 0) * 512 + col]) : (ushort_t)0;
    v.y = (k4 + 1 < 1489) ? f2b(P.fc1_w[(size_t)(k4 + 1) * 512 + col]) : (ushort_t)0;
    v.z = (k4 + 2 < 1489) ? f2b(P.fc1_w[(size_t)(k4 + 2) * 512 + col]) : (ushort_t)0;
    v.w = (k4 + 3 < 1489) ? f2b(P.fc1_w[(size_t)(k4 + 3) * 512 + col]) : (ushort_t)0;
    *(ushort4*)&P.fc1t[(size_t)col * KPF + k4] = v;
    return;
  }
  bid -= 768;
  if (bid < 1536) {  // 6x 512x512 transposes
    int y = bid >> 8;
    int o = (bid & 255) * 256 + t;
    const float* W = y == 0 ? P.W_out : y == 1 ? P.fc2_w : y == 2 ? P.q_w
                   : y == 3 ? P.v_w : y == 4 ? P.o_w : P.ffn1_w;
    ushort_t* Wt = y == 0 ? P.Wot : y == 1 ? P.fc2t : y == 2 ? P.qwt
                 : y == 3 ? P.vwt : y == 4 ? P.owt : P.f1t;
    int col = o >> 7, k4 = (o & 127) * 4;
    ushort4 v;
    v.x = f2b(W[(size_t)(k4 + 0) * 512 + col]);
    v.y = f2b(W[(size_t)(k4 + 1) * 512 + col]);
    v.z = f2b(W[(size_t)(k4 + 2) * 512 + col]);
    v.w = f2b(W[(size_t)(k4 + 3) * 512 + col]);
    *(ushort4*)&Wt[(size_t)col * 512 + k4] = v;
    return;
  }
  bid -= 1536;
  if (bid < 12288) {  // hb
    int o = bid * 256 + t;
    int row = o / 48, c4 = (o - row * 48) * 4;
    const float* hr = P.h + (size_t)row * 133;
    ushort4 v;
    v.x = (c4 + 0 < 133) ? f2b(hr[c4 + 0]) : (ushort_t)0;
    v.y = (c4 + 1 < 133) ? f2b(hr[c4 + 1]) : (ushort_t)0;
    v.z = (c4 + 2 < 133) ? f2b(hr[c4 + 2]) : (ushort_t)0;
    v.w = (c4 + 3 < 133) ? f2b(hr[c4 + 3]) : (ushort_t)0;
    *(ushort4*)&P.hb[(size_t)row * KP1 + c4] = v;
    return;
  }
  bid -= 12288;
  {  // em
    size_t o = ((size_t)bid * 256 + t) * 4;
    float4 e = *(const float4*)&P.edge[o];
    int4 a = *(const int4*)&P.adj[o];
    ushort4 v;
    v.x = a.x > 0 ? f2b(e.x) : (ushort_t)MINF_BF16;
    v.y = a.y > 0 ? f2b(e.y) : (ushort_t)MINF_BF16;
    v.z = a.z > 0 ? f2b(e.z) : (ushort_t)MINF_BF16;
    v.w = a.w > 0 ? f2b(e.w) : (ushort_t)MINF_BF16;
    *(ushort4*)&P.em[o] = v;
  }
}

// ---------------------------------------------------------------------------
// GAT layer 1 body. id in [0, 8*C): xcd=id&7, head=(id>>3)&7,
// bl=((id>>6)<<3)|(id&7). s1/s2 ride the MFMA via wh12 B-columns.
__device__ void gat1_body(int id, int base, const MP& P, LdsGat1& L) {
  const int hh = (id >> 3) & 7;
  const int bl = ((id >> 6) << 3) | (id & 7);
  const int bg = base + bl;
  const int t = threadIdx.x;
  const int lane = t & 63, w = t >> 6;
  const int l16 = lane & 15, quad = lane >> 4;
  const int w8 = w * 8, sr8 = (t >> 3) & 7;
  const int csw = ((t & 7) ^ sr8) << 3;  // pre-swizzled source column

  if (t < 96)
    *(ushort4*)&(&L.wh12s[0][0])[t * 4] =
        *(const ushort4*)&P.wh12[hh * 384 + t * 4];

  const ushort_t* gA = P.hb + (size_t)(bg * 128 + w8 + sr8) * KP1 + csw;
  const ushort_t* gB = P.W2t + (size_t)(hh * 64 + w8 + sr8) * KP1 + csw;
  ffrag acc[2][4];
  ffrag acc_s[2];
#pragma unroll
  for (int mi = 0; mi < 2; ++mi) {
    acc_s[mi] = {0.f, 0.f, 0.f, 0.f};
#pragma unroll
    for (int ni = 0; ni < 4; ++ni) acc[mi][ni] = {0.f, 0.f, 0.f, 0.f};
  }
  for (int k0 = 0; k0 < KP1; k0 += 64) {
    __syncthreads();
#pragma unroll
    for (int p = 0; p < 4; ++p)
      gll16(gA + (size_t)(p * 32) * KP1 + k0, &L.u.g.As[p * 32 + w8][0]);
#pragma unroll
    for (int p = 0; p < 2; ++p)
      gll16(gB + (size_t)(p * 32) * KP1 + k0, &L.u.g.Bs[p * 32 + w8][0]);
    __syncthreads();
#pragma unroll
    for (int ks = 0; ks < 2; ++ks) {
      const int cs = ((ks * 4 + quad) ^ (l16 & 7)) << 3;  // swizzled read
      bfrag af[2], bf[4];
      bfrag bs = {0, 0, 0, 0, 0, 0, 0, 0};
      if (l16 < 2)
        bs = *(const bfrag*)&L.wh12s[l16][k0 + ks * 32 + quad * 8];
#pragma unroll
      for (int mi = 0; mi < 2; ++mi)
        af[mi] = *(const bfrag*)&L.u.g.As[w * 32 + mi * 16 + l16][cs];
#pragma unroll
      for (int ni = 0; ni < 4; ++ni)
        bf[ni] = *(const bfrag*)&L.u.g.Bs[ni * 16 + l16][cs];
#pragma unroll
      for (int mi = 0; mi < 2; ++mi) {
#pragma unroll
        for (int ni = 0; ni < 4; ++ni)
          acc[mi][ni] = __builtin_amdgcn_mfma_f32_16x16x32_bf16(
              af[mi], bf[ni], acc[mi][ni], 0, 0, 0);
        acc_s[mi] = __builtin_amdgcn_mfma_f32_16x16x32_bf16(
            af[mi], bs, acc_s[mi], 0, 0, 0);
      }
    }
  }
  __syncthreads();  // staging dead; LDS becomes WS

#pragma unroll
  for (int mi = 0; mi < 2; ++mi)
#pragma unroll
    for (int ni = 0; ni < 4; ++ni) {
      int col = ni * 16 + l16;
      int rowb = w * 32 + mi * 16 + quad * 4;
      uint2 pv;
      pv.x = cvt_pk(acc[mi][ni][0], acc[mi][ni][1]);
      pv.y = cvt_pk(acc[mi][ni][2], acc[mi][ni][3]);
      *(uint2*)&L.u.WS[col][rowb] = pv;
    }
  if (l16 < 2) {
    float* sp = (l16 == 0) ? L.ss1 : L.ss2;
#pragma unroll
    for (int mi = 0; mi < 2; ++mi)
#pragma unroll
      for (int r = 0; r < 4; ++r)
        sp[w * 32 + mi * 16 + quad * 4 + r] = acc_s[mi][r] * LOG2E;
  }
  uint4 ereg[2][4];
  {
    const ushort_t* em = P.em + (size_t)bg * 16384;
#pragma unroll
    for (int mi = 0; mi < 2; ++mi) {
      int row = w * 32 + mi * 16 + l16;
#pragma unroll
      for (int ks = 0; ks < 4; ++ks)
        ereg[mi][ks] = *(const uint4*)&em[row * 128 + ks * 32 + quad * 8];
    }
  }
  __syncthreads();

  const float aeh2 = P.aeh[hh] * LOG2E;
  float rs1[2];
  rs1[0] = L.ss1[w * 32 + l16];
  rs1[1] = L.ss1[w * 32 + 16 + l16];
  uint4 aw[2][4];
#pragma unroll
  for (int mi = 0; mi < 2; ++mi) {
#pragma unroll
    for (int ks = 0; ks < 4; ++ks) {
      float s2v[8];
      *(float4*)&s2v[0] = *(const float4*)&L.ss2[ks * 32 + quad * 8];
      *(float4*)&s2v[4] = *(const float4*)&L.ss2[ks * 32 + quad * 8 + 4];
      const unsigned uu[4] = {ereg[mi][ks].x, ereg[mi][ks].y,
                              ereg[mi][ks].z, ereg[mi][ks].w};
      unsigned po[4];
#pragma unroll
      for (int pr = 0; pr < 4; ++pr) {
        float elo = __uint_as_float(uu[pr] << 16);
        float ehi = __uint_as_float(uu[pr] & 0xffff0000u);
        float e0 = fmaf(elo, aeh2, rs1[mi] + s2v[pr * 2]);
        float e1 = fmaf(ehi, aeh2, rs1[mi] + s2v[pr * 2 + 1]);
        e0 = fmaxf(e0, ALPHA_LK * e0);
        e1 = fmaxf(e1, ALPHA_LK * e1);
        float p0 = (elo != -INFINITY) ? fexp2(e0) : 0.f;
        float p1 = (ehi != -INFINITY) ? fexp2(e1) : 0.f;
        po[pr] = cvt_pk(p0, p1);
      }
      aw[mi][ks] = make_uint4(po[0], po[1], po[2], po[3]);
    }
  }

  bfrag bones;
#pragma unroll
  for (int i = 0; i < 8; ++i) bones[i] = (short)0x3F80;

  ffrag acc2[2][4];
  ffrag accs[2];
#pragma unroll
  for (int mi = 0; mi < 2; ++mi) {
    accs[mi] = {0.f, 0.f, 0.f, 0.f};
#pragma unroll
    for (int ni = 0; ni < 4; ++ni) acc2[mi][ni] = {0.f, 0.f, 0.f, 0.f};
  }
#pragma unroll
  for (int ks = 0; ks < 4; ++ks) {
    bfrag bfr[4];
#pragma unroll
    for (int ni = 0; ni < 4; ++ni)
      bfr[ni] = *(const bfrag*)&L.u.WS[ni * 16 + l16][ks * 32 + quad * 8];
#pragma unroll
    for (int mi = 0; mi < 2; ++mi) {
      bfrag afr;
      __builtin_memcpy(&afr, &aw[mi][ks], 16);
#pragma unroll
      for (int ni = 0; ni < 4; ++ni)
        acc2[mi][ni] = __builtin_amdgcn_mfma_f32_16x16x32_bf16(
            afr, bfr[ni], acc2[mi][ni], 0, 0, 0);
      accs[mi] = __builtin_amdgcn_mfma_f32_16x16x32_bf16(
          afr, bones, accs[mi], 0, 0, 0);
    }
  }
  float sv[2][4];
#pragma unroll
  for (int mi = 0; mi < 2; ++mi)
#pragma unroll
    for (int r = 0; r < 4; ++r)
      sv[mi][r] = frcp(fmaxf(accs[mi][r], 1e-30f));

#pragma unroll
  for (int mi = 0; mi < 2; ++mi)
#pragma unroll
    for (int ni = 0; ni < 4; ++ni) {
      float e0 = elu1(acc2[mi][ni][0] * sv[mi][0]);
      float e1 = elu1(acc2[mi][ni][1] * sv[mi][1]);
      float e2 = elu1(acc2[mi][ni][2] * sv[mi][2]);
      float e3 = elu1(acc2[mi][ni][3] * sv[mi][3]);
      unsigned p01 = cvt_pk(e0, e1), p23 = cvt_pk(e2, e3);
      int rl = w * 32 + mi * 16 + quad * 4;
      size_t bo = (size_t)(bl * 128 + rl) * 512 + hh * 64 + ni * 16 + l16;
      P.xb[bo] = (ushort_t)p01;
      P.xb[bo + 512] = (ushort_t)(p01 >> 16);
      P.xb[bo + 1024] = (ushort_t)p23;
      P.xb[bo + 1536] = (ushort_t)(p23 >> 16);
    }
}

// ---------------------------------------------------------------------------
// att2t body: t1/t2 (2 thr/row, wa in LDS) then softmax -> aw bf16 + sinv.
__device__ void att2t_body(int bl, int base, const MP& P, LdsAtt& L) {
  const int bg = base + bl;
  const int t = threadIdx.x;
  L.was1[t] = P.wa1[t]; L.was1[t + 256] = P.wa1[t + 256];
  L.was2[t] = P.wa2[t]; L.was2[t + 256] = P.wa2[t + 256];
  __syncthreads();
  const int row = t >> 1, half = t & 1;
  {
    const ushort_t* xr = P.xb + (size_t)(bl * 128 + row) * 512 + half * 256;
    float p1 = 0.f, p2 = 0.f;
#pragma unroll 4
    for (int i = 0; i < 32; ++i) {
      uint4 u = *(const uint4*)&xr[i * 8];
      const unsigned uu[4] = {u.x, u.y, u.z, u.w};
#pragma unroll
      for (int pr = 0; pr < 4; ++pr) {
        float lo = __uint_as_float(uu[pr] << 16);
        float hi = __uint_as_float(uu[pr] & 0xffff0000u);
        int c = half * 256 + i * 8 + pr * 2;
        p1 = fmaf(lo, L.was1[c], p1); p1 = fmaf(hi, L.was1[c + 1], p1);
        p2 = fmaf(lo, L.was2[c], p2); p2 = fmaf(hi, L.was2[c + 1], p2);
      }
    }
    p1 += __shfl_xor(p1, 1);
    p2 += __shfl_xor(p2, 1);
    if (!half) { L.t1s[row] = p1 * LOG2E; L.t2s[row] = p2 * LOG2E; }
  }
  __syncthreads();
  const float ae2 = P.aeo[0] * LOG2E;
  const float rt1 = L.t1s[row];
  const ushort_t* emr = P.em + (size_t)bg * 16384 + row * 128 + half * 64;
  ushort_t* awr = P.awg + (size_t)bl * 16384 + row * 128 + half * 64;
  float s = 0.f;
#pragma unroll
  for (int v = 0; v < 8; ++v) {
    uint4 eu = *(const uint4*)&emr[v * 8];
    const unsigned uu[4] = {eu.x, eu.y, eu.z, eu.w};
    unsigned po[4];
#pragma unroll
    for (int pr = 0; pr < 4; ++pr) {
      float elo = __uint_as_float(uu[pr] << 16);
      float ehi = __uint_as_float(uu[pr] & 0xffff0000u);
      float e0 = fmaf(elo, ae2, rt1 + L.t2s[half * 64 + v * 8 + pr * 2]);
      float e1 = fmaf(ehi, ae2, rt1 + L.t2s[half * 64 + v * 8 + pr * 2 + 1]);
      e0 = fmaxf(e0, ALPHA_LK * e0);
      e1 = fmaxf(e1, ALPHA_LK * e1);
      float p0 = (elo != -INFINITY) ? fexp2(e0) : 0.f;
      float p1 = (ehi != -INFINITY) ? fexp2(e1) : 0.f;
      unsigned q = cvt_pk(p0, p1);
      po[pr] = q;
      s += __uint_as_float(q << 16) + __uint_as_float(q & 0xffff0000u);
    }
    *(uint4*)&awr[v * 8] = make_uint4(po[0], po[1], po[2], po[3]);
  }
  s += __shfl_xor(s, 1);
  if (!half) P.sinv[(size_t)bl * 128 + row] = 1.f / fmaxf(s, 1e-30f);
}

// ---------------------------------------------------------------------------
// GAT output layer body. id in [0, 4*C): xcd=id&7, sp2=(id>>3)&3,
// bl=((id>>5)<<3)|(id&7).
__device__ void gat2_body(int id, int base, const MP& P, LdsGat2& L) {
  const int sp2 = (id >> 3) & 3;
  const int bl = ((id >> 5) << 3) | (id & 7);
  const int bg = base + bl;
  const int t = threadIdx.x;
  const int lane = t & 63, w = t >> 6;
  const int wm = w >> 1, wn = w & 1;
  const int l16 = lane & 15, quad = lane >> 4;
  const int w8 = w * 8, sr8 = (t >> 3) & 7;
  const int csw = ((t & 7) ^ sr8) << 3;

  const ushort_t* gA = P.xb + (size_t)(bl * 128 + w8 + sr8) * 512 + csw;
  const ushort_t* gB = P.Wot + (size_t)(sp2 * 128 + w8 + sr8) * 512 + csw;
  ffrag acc[4][4];
#pragma unroll
  for (int mi = 0; mi < 4; ++mi)
#pragma unroll
    for (int ni = 0; ni < 4; ++ni) acc[mi][ni] = {0.f, 0.f, 0.f, 0.f};
  for (int k0 = 0; k0 < 512; k0 += 64) {
    __syncthreads();
#pragma unroll
    for (int p = 0; p < 4; ++p) {
      gll16(gA + (size_t)(p * 32) * 512 + k0, &L.u.g.As[p * 32 + w8][0]);
      gll16(gB + (size_t)(p * 32) * 512 + k0, &L.u.g.Bs[p * 32 + w8][0]);
    }
    __syncthreads();
#pragma unroll
    for (int ks = 0; ks < 2; ++ks) {
      const int cs = ((ks * 4 + quad) ^ (l16 & 7)) << 3;
      bfrag af[4], bf[4];
#pragma unroll
      for (int i = 0; i < 4; ++i) {
        af[i] = *(const bfrag*)&L.u.g.As[wm * 64 + i * 16 + l16][cs];
        bf[i] = *(const bfrag*)&L.u.g.Bs[wn * 64 + i * 16 + l16][cs];
      }
#pragma unroll
      for (int mi = 0; mi < 4; ++mi)
#pragma unroll
        for (int ni = 0; ni < 4; ++ni)
          acc[mi][ni] = __builtin_amdgcn_mfma_f32_16x16x32_bf16(
              af[mi], bf[ni], acc[mi][ni], 0, 0, 0);
    }
  }
  __syncthreads();

#pragma unroll
  for (int mi = 0; mi < 4; ++mi)
#pragma unroll
    for (int ni = 0; ni < 4; ++ni) {
      int col = wn * 64 + ni * 16 + l16;
      int rowb = wm * 64 + mi * 16 + quad * 4;
      uint2 pv;
      pv.x = cvt_pk(acc[mi][ni][0], acc[mi][ni][1]);
      pv.y = cvt_pk(acc[mi][ni][2], acc[mi][ni][3]);
      *(uint2*)&L.u.WS[col][rowb] = pv;
    }
  __syncthreads();

  uint4 awf[2][4];
  float sv[2][4];
  {
    const ushort_t* ap = P.awg + (size_t)bl * 16384;
#pragma unroll
    for (int mi = 0; mi < 2; ++mi) {
      int row = w * 32 + mi * 16 + l16;
#pragma unroll
      for (int ks = 0; ks < 4; ++ks)
        awf[mi][ks] = *(const uint4*)&ap[row * 128 + ks * 32 + quad * 8];
      float si = P.sinv[(size_t)bl * 128 + row];
#pragma unroll
      for (int r = 0; r < 4; ++r) sv[mi][r] = __shfl(si, quad * 4 + r);
    }
  }

  for (int s0 = 0; s0 < 2; ++s0) {
    ffrag acc2[2][4];
#pragma unroll
    for (int mi = 0; mi < 2; ++mi)
#pragma unroll
      for (int ni = 0; ni < 4; ++ni) acc2[mi][ni] = {0.f, 0.f, 0.f, 0.f};
#pragma unroll
    for (int ks = 0; ks < 4; ++ks) {
      bfrag bfr[4];
#pragma unroll
      for (int ni = 0; ni < 4; ++ni)
        bfr[ni] = *(const bfrag*)&L.u.WS[s0 * 64 + ni * 16 + l16][ks * 32 + quad * 8];
#pragma unroll
      for (int mi = 0; mi < 2; ++mi) {
        bfrag afr;
        __builtin_memcpy(&afr, &awf[mi][ks], 16);
#pragma unroll
        for (int ni = 0; ni < 4; ++ni)
          acc2[mi][ni] = __builtin_amdgcn_mfma_f32_16x16x32_bf16(
              afr, bfr[ni], acc2[mi][ni], 0, 0, 0);
      }
    }
    __syncthreads();
#pragma unroll
    for (int ni = 0; ni < 4; ++ni) {
      float s = 0.f;
#pragma unroll
      for (int mi = 0; mi < 2; ++mi)
#pragma unroll
        for (int r = 0; r < 4; ++r) s += elu1(acc2[mi][ni][r] * sv[mi][r]);
      s += __shfl_xor(s, 16);
      s += __shfl_xor(s, 32);
      if (quad == 0) L.ps[w][ni * 16 + l16] = s;
    }
    __syncthreads();
    if (t < 64) {
      float s = L.ps[0][t] + L.ps[1][t] + L.ps[2][t] + L.ps[3][t];
      P.gatb[(size_t)bg * 512 + sp2 * 128 + s0 * 64 + t] = f2b(s * (1.f / 128.f));
    }
  }
}

// ---------------------------------------------------------------------------
__device__ void tail_kloop(const ushort_t* A, const ushort_t* Bt, int K, int ld,
                           ushort_t (*As)[64], ushort_t (*Bs)[64],
                           ffrag (*acc)[4], int row0, int col0, int t) {
  const int lane = t & 63, w = t >> 6;
  const int wm = w >> 1, wn = w & 1;
  const int l16 = lane & 15, quad = lane >> 4;
  const int w8 = w * 8, sr8 = (t >> 3) & 7;
  const int csw = ((t & 7) ^ sr8) << 3;
  const ushort_t* gA = A + (size_t)(row0 + w8 + sr8) * ld + csw;
  const ushort_t* gB = Bt + (size_t)(col0 + w8 + sr8) * ld + csw;
  for (int k0 = 0; k0 < K; k0 += 64) {
    __syncthreads();
#pragma unroll
    for (int p = 0; p < 4; ++p) {
      gll16(gA + (size_t)(p * 32) * ld + k0, &As[p * 32 + w8][0]);
      gll16(gB + (size_t)(p * 32) * ld + k0, &Bs[p * 32 + w8][0]);
    }
    __syncthreads();
#pragma unroll
    for (int ks = 0; ks < 2; ++ks) {
      const int cs = ((ks * 4 + quad) ^ (l16 & 7)) << 3;
      bfrag af[4], bf[4];
#pragma unroll
      for (int i = 0; i < 4; ++i) {
        af[i] = *(const bfrag*)&As[wm * 64 + i * 16 + l16][cs];
        bf[i] = *(const bfrag*)&Bs[wn * 64 + i * 16 + l16][cs];
      }
#pragma unroll
      for (int mi = 0; mi < 4; ++mi)
#pragma unroll
        for (int ni = 0; ni < 4; ++ni)
          acc[mi][ni] = __builtin_amdgcn_mfma_f32_16x16x32_bf16(
              af[mi], bf[ni], acc[mi][ni], 0, 0, 0);
    }
  }
}

// one 128x128 tile of C = act(A1@Bt1^T (+A2@Bt2^T) + bias). vb in [0,16).
__device__ void tailg_body(int vb, const ushort_t* A1, const ushort_t* Bt1,
                           int K1, int ld1, const ushort_t* A2,
                           const ushort_t* Bt2, const float* bias,
                           ushort_t* Cc, int DUAL, int RELU, LdsTail& L) {
  const int t = threadIdx.x;
  const int lane = t & 63, w = t >> 6;
  const int wm = w >> 1, wn = w & 1;
  const int l16 = lane & 15, quad = lane >> 4;
  const int row0 = (vb >> 2) * 128, col0 = (vb & 3) * 128;

  ffrag acc[4][4];
#pragma unroll
  for (int mi = 0; mi < 4; ++mi)
#pragma unroll
    for (int ni = 0; ni < 4; ++ni) acc[mi][ni] = {0.f, 0.f, 0.f, 0.f};

  tail_kloop(A1, Bt1, K1, ld1, L.As, L.Bs, acc, row0, col0, t);
  if (DUAL) tail_kloop(A2, Bt2, 512, 512, L.As, L.Bs, acc, row0, col0, t);

#pragma unroll
  for (int mi = 0; mi < 4; ++mi)
#pragma unroll
    for (int ni = 0; ni < 4; ++ni) {
      int col = col0 + wn * 64 + ni * 16 + l16;
      float bb = bias[col];
      float v0 = acc[mi][ni][0] + bb, v1 = acc[mi][ni][1] + bb;
      float v2 = acc[mi][ni][2] + bb, v3 = acc[mi][ni][3] + bb;
      if (RELU) {
        v0 = fmaxf(v0, 0.f); v1 = fmaxf(v1, 0.f);
        v2 = fmaxf(v2, 0.f); v3 = fmaxf(v3, 0.f);
      }
      unsigned p01 = cvt_pk(v0, v1), p23 = cvt_pk(v2, v3);
      int row = row0 + wm * 64 + mi * 16 + quad * 4;
      size_t o = (size_t)row * 512 + col;
      Cc[o] = (ushort_t)p01;
      Cc[o + 512] = (ushort_t)(p01 >> 16);
      Cc[o + 1024] = (ushort_t)p23;
      Cc[o + 1536] = (ushort_t)(p23 >> 16);
    }
}

// out[512][12] = fb5 @ ffn2_w + b. vb in [0,128), 4 rows per vb.
__device__ void ffn2_body(int vb, const MP& P) {
  int wv = threadIdx.x >> 6, lane = threadIdx.x & 63;
  int row = vb * 4 + wv;
  const ushort_t* fr = P.fb5 + (size_t)row * 512;
  float v[8];
  ushort4 u0 = *(const ushort4*)&fr[lane * 8];
  ushort4 u1 = *(const ushort4*)&fr[lane * 8 + 4];
  v[0] = b2f(u0.x); v[1] = b2f(u0.y); v[2] = b2f(u0.z); v[3] = b2f(u0.w);
  v[4] = b2f(u1.x); v[5] = b2f(u1.y); v[6] = b2f(u1.z); v[7] = b2f(u1.w);
#pragma unroll
  for (int j = 0; j < 12; ++j) {
    float s = 0.f;
#pragma unroll
    for (int i = 0; i < 8; ++i)
      s += v[i] * P.ffn2_w[(size_t)(lane * 8 + i) * 12 + j];
#pragma unroll
    for (int off = 32; off; off >>= 1) s += __shfl_down(s, off);
    if (lane == 0) P.out[(size_t)row * 12 + j] = s + P.ffn2_b[j];
  }
}

// ---------------------------------------------------------------------------
__global__ __launch_bounds__(256) void k_prep(MP P) { prep_body(blockIdx.x, P); }

__global__ __launch_bounds__(256) void k_gat1(MP P, int base) {
  __shared__ LdsGat1 L;
  gat1_body(blockIdx.x, base, P, L);
}

// att2t launch; last 16 blocks (base==0 only) compute fb1 tiles.
__global__ __launch_bounds__(256) void k_att(MP P, int base) {
  __shared__ union { LdsAtt at; LdsTail tl; } L;
  int b = blockIdx.x;
  if (b < P.C) att2t_body(b, base, P, L.at);
  else tailg_body(b - P.C, P.fpb, P.fc1t, KPF, KPF, nullptr, nullptr,
                  P.fc1_b, P.fb1, 0, 1, L.tl);
}

// gat2 launch; last 16 blocks (base==0 only) compute fb2 tiles.
__global__ __launch_bounds__(256) void k_gat2(MP P, int base) {
  __shared__ union { LdsGat2 g2; LdsTail tl; } L;
  int b = blockIdx.x;
  if (b < 4 * P.C) gat2_body(b, base, P, L.g2);
  else tailg_body(b - 4 * P.C, P.fb1, P.fc2t, 512, 512, nullptr, nullptr,
                  P.fc2_b, P.fb2, 0, 0, L.tl);
}

// persistent 16-block kernel: fb3 -> fb4 -> fb5 -> ffn2 with atomic barriers.
__global__ __launch_bounds__(256) void k_tail6(MP P) {
  __shared__ LdsTail L;
  int b = blockIdx.x;
  tailg_body(b, P.gatb, P.qwt, 512, 512, P.fb2, P.vwt, P.qvb, P.fb3, 1, 0, L);
  tbar(P.cnt, 16);
  tailg_body(b, P.fb3, P.owt, 512, 512, nullptr, nullptr, P.o_b, P.fb4, 0, 1, L);
  tbar(P.cnt, 32);
  tailg_body(b, P.fb4, P.f1t, 512, 512, nullptr, nullptr, P.ffn1_b, P.fb5, 0, 1, L);
  tbar(P.cnt, 48);
  for (int vb = b; vb < 128; vb += 16) ffn2_body(vb, P);
}

// ---------------------------------------------------------------------------
extern "C" void kernel_launch(void* const* d_in, const int* in_sizes, int n_in,
                              void* d_out, int out_size, void* d_ws, size_t ws_size,
                              hipStream_t stream) {
  MP P;
  P.h        = (const float*)d_in[0];
  P.adj      = (const int*)d_in[1];
  P.edge     = (const float*)d_in[2];
  P.fp       = (const float*)d_in[3];
  P.Whd      = (const float*)d_in[4];
  P.a1h      = (const float*)d_in[5];
  P.a2h      = (const float*)d_in[6];
  P.aeh      = (const float*)d_in[7];
  P.W_out    = (const float*)d_in[8];
  P.a1o      = (const float*)d_in[9];
  P.a2o      = (const float*)d_in[10];
  P.aeo      = (const float*)d_in[11];
  P.fc1_w    = (const float*)d_in[12];
  P.fc1_b    = (const float*)d_in[13];
  P.fc2_w    = (const float*)d_in[14];
  P.fc2_b    = (const float*)d_in[15];
  P.q_w      = (const float*)d_in[16];
  P.q_b      = (const float*)d_in[17];
  // k_w/k_b (18,19) dead: softmax over size-1 axis == 1 => fused = q + v
  P.v_w      = (const float*)d_in[20];
  P.v_b      = (const float*)d_in[21];
  P.o_w      = (const float*)d_in[22];
  P.o_b      = (const float*)d_in[23];
  P.ffn1_w   = (const float*)d_in[24];
  P.ffn1_b   = (const float*)d_in[25];
  P.ffn2_w   = (const float*)d_in[26];
  P.ffn2_b   = (const float*)d_in[27];
  P.out      = (float*)d_out;

  // ---- workspace carve (R5 layout + cnt) ----
  const size_t hb_bytes = (size_t)65536 * KP1 * 2;
  const size_t em_bytes = (size_t)512 * 16384 * 2;
  const size_t tail_bytes =
      (size_t)512 * KPF * 2 * 2 + (size_t)512 * 512 * 2 * 12 + 2048;
  const size_t fixed_bytes = hb_bytes + em_bytes + (size_t)512 * KP1 * 2 +
                             (size_t)2 * 65536 * 4 + tail_bytes + 16384;
  int C = 32;
  for (int cand = 512; cand >= 32; cand >>= 1) {
    size_t need = (size_t)cand * (131072 + 32768 + 512) + fixed_bytes;
    if (need <= ws_size) { C = cand; break; }
  }
  P.C = C;

  char* p = (char*)d_ws;
  P.xb  = (ushort_t*)p; p += (size_t)C * 65536 * 2;
  P.awg = (ushort_t*)p; p += (size_t)C * 16384 * 2;
  P.sinv = (float*)p;   p += (size_t)C * 128 * 4;
  P.hb  = (ushort_t*)p; p += hb_bytes;
  P.em  = (ushort_t*)p; p += em_bytes;
  P.W2t = (ushort_t*)p; p += (size_t)512 * KP1 * 2;
  P.wh12 = (ushort_t*)p; p += 8 * 384 * 2;
  p += 2 * 65536 * 4 - 8 * 384 * 2;
  P.fpb  = (ushort_t*)p; p += (size_t)512 * KPF * 2;
  P.fc1t = (ushort_t*)p; p += (size_t)512 * KPF * 2;
  P.Wot  = (ushort_t*)p; p += (size_t)512 * 512 * 2;
  P.fc2t = (ushort_t*)p; p += (size_t)512 * 512 * 2;
  P.qwt  = (ushort_t*)p; p += (size_t)512 * 512 * 2;
  P.vwt  = (ushort_t*)p; p += (size_t)512 * 512 * 2;
  P.owt  = (ushort_t*)p; p += (size_t)512 * 512 * 2;
  P.f1t  = (ushort_t*)p; p += (size_t)512 * 512 * 2;
  P.gatb = (ushort_t*)p; p += (size_t)512 * 512 * 2;
  P.fb1  = (ushort_t*)p; p += (size_t)512 * 512 * 2;
  P.fb2  = (ushort_t*)p; p += (size_t)512 * 512 * 2;
  P.fb3  = (ushort_t*)p; p += (size_t)512 * 512 * 2;
  P.fb4  = (ushort_t*)p; p += (size_t)512 * 512 * 2;
  P.fb5  = (ushort_t*)p; p += (size_t)512 * 512 * 2;
  P.qvb  = (float*)p; p += 2048;
  P.wa1  = (float*)p; p += 2048;
  P.wa2  = (float*)p; p += 2048;
  P.cnt  = (unsigned*)p; p += 64;

  // 5 dispatches total (C=512 case)
  k_prep<<<23786, 256, 0, stream>>>(P);
  for (int base = 0; base < 512; base += C) {
    int r = (base == 0) ? 16 : 0;
    k_gat1<<<8 * C, 256, 0, stream>>>(P, base);
    k_att<<<C + r, 256, 0, stream>>>(P, base);
    k_gat2<<<4 * C + r, 256, 0, stream>>>(P, base);
  }
  k_tail6<<<16, 256, 0, stream>>>(P);
}

// Round 9
// 487.676 us; speedup vs baseline: 1.1996x; 1.1996x over previous
//
#include <hip/hip_runtime.h>
#include <hip/hip_bf16.h>

// FPGNN forward for MI355X. Round 21 == Round 20 resubmitted verbatim
// (R8 bench was a GPUAcquisitionTimeout; kernel never ran).
// R20: revert R7's persistent atomic-barrier tail (161us, 97% idle --
// cross-XCD atomic RMW spin is pathological). Keep R5 structure + the two
// safe ride-alongs (fb1 in att launch, fb2 in gat2 launch). Tail = 4 plain
// stream-ordered launches. 8 dispatches.
// Shapes: B=512, N=128, F_IN=133, NHEADS=8, NHID=64, HID=512, FP_DIM=1489, TASKS=12

#define ALPHA_LK 0.2f
#define LOG2E 1.44269504f
#define KP1 192   // F_IN=133 padded to 3*64
#define KPF 1536  // FP_DIM=1489 padded to 24*64
#define MINF_BF16 0xFF80u

typedef unsigned short ushort_t;
typedef __attribute__((ext_vector_type(8))) short bfrag;   // 8 x bf16 (4 VGPRs)
typedef __attribute__((ext_vector_type(4))) float ffrag;   // 4 x f32 acc

__device__ __forceinline__ float b2f(ushort_t u) {
  return __uint_as_float(((unsigned)u) << 16);
}
__device__ __forceinline__ ushort_t f2b(float f) {
  unsigned u = __float_as_uint(f);
  unsigned r = (u + 0x7fffu + ((u >> 16) & 1u)) >> 16;  // RNE
  return (ushort_t)r;
}
__device__ __forceinline__ unsigned cvt_pk(float lo, float hi) {
  unsigned r;
  asm("v_cvt_pk_bf16_f32 %0, %1, %2" : "=v"(r) : "v"(lo), "v"(hi));
  return r;
}
__device__ __forceinline__ float frcp(float x) {
  float r;
  asm("v_rcp_f32 %0, %1" : "=v"(r) : "v"(x));
  return r;
}
__device__ __forceinline__ float fexp2(float x) {
#if __has_builtin(__builtin_amdgcn_exp2f)
  return __builtin_amdgcn_exp2f(x);
#else
  return exp2f(x);
#endif
}
__device__ __forceinline__ float elu1(float v) {
  return v > 0.f ? v : __expf(v) - 1.f;
}
__device__ __forceinline__ void gll16(const void* g, void* l) {
  __builtin_amdgcn_global_load_lds(
      (const __attribute__((address_space(1))) unsigned int*)(unsigned long long)g,
      (__attribute__((address_space(3))) unsigned int*)(unsigned long long)l,
      16, 0, 0);
}

// ---------------------------------------------------------------------------
struct MP {
  const float *h; const int *adj; const float *edge; const float *fp;
  const float *Whd, *a1h, *a2h, *aeh;
  const float *W_out, *a1o, *a2o, *aeo;
  const float *fc1_w, *fc1_b, *fc2_w, *fc2_b;
  const float *q_b, *v_b, *q_w, *v_w, *o_w, *o_b;
  const float *ffn1_w, *ffn1_b, *ffn2_w, *ffn2_b;
  ushort_t *hb, *em, *W2t, *wh12, *fpb, *fc1t, *Wot, *fc2t, *qwt, *vwt, *owt, *f1t;
  ushort_t *xb, *awg; float *sinv;
  ushort_t *gatb, *fb1, *fb2, *fb3, *fb4, *fb5;
  float *wa1, *wa2, *qvb; float *out;
  int C;
};

struct LdsGat1 {
  union { struct { ushort_t As[128][64]; ushort_t Bs[64][64]; } g;
          ushort_t WS[64][136]; } u;
  float ss1[128], ss2[128];
  ushort_t wh12s[2][192];
};
struct LdsGat2 {
  union { struct { ushort_t As[128][64]; ushort_t Bs[128][64]; } g;
          ushort_t WS[128][136]; } u;
  float ps[4][64];
};
struct LdsAtt { float t1s[128], t2s[128], was1[512], was2[512]; };
struct LdsTail { ushort_t As[128][64]; ushort_t Bs[128][64]; };

// ---------------------------------------------------------------------------
// prep: all preamble work, segmented by block id (23786 total).
__device__ void prep_body(int bid, const MP& P) {
  const int t = threadIdx.x;
  if (bid < 8) {  // wh12
    int hh = bid;
    if (t < 192) {
      float s1 = 0.f, s2 = 0.f;
      if (t < 133) {
        const float* wr = P.Whd + (size_t)(hh * 133 + t) * 64;
        const float* a1r = P.a1h + hh * 64;
        const float* a2r = P.a2h + hh * 64;
#pragma unroll 8
        for (int d = 0; d < 64; ++d) {
          float wv = wr[d];
          s1 += wv * a1r[d];
          s2 += wv * a2r[d];
        }
      }
      P.wh12[hh * 384 + t] = f2b(s1);
      P.wh12[hh * 384 + 192 + t] = f2b(s2);
    }
    return;
  }
  bid -= 8;
  if (bid < 128) {  // wa12
    int wv = t >> 6, lane = t & 63;
    int k = bid * 4 + wv;
    const float* wr = P.W_out + (size_t)k * 512;
    float p1 = 0.f, p2 = 0.f;
#pragma unroll
    for (int i = 0; i < 8; ++i) {
      float v = wr[lane + i * 64];
      p1 += v * P.a1o[lane + i * 64];
      p2 += v * P.a2o[lane + i * 64];
    }
#pragma unroll
    for (int off = 32; off; off >>= 1) {
      p1 += __shfl_down(p1, off);
      p2 += __shfl_down(p2, off);
    }
    if (lane == 0) { P.wa1[k] = p1; P.wa2[k] = p2; }
    return;
  }
  bid -= 128;
  if (bid < 2) {  // qvb
    int o = bid * 256 + t;
    P.qvb[o] = P.q_b[o] + P.v_b[o];
    return;
  }
  bid -= 2;
  if (bid < 96) {  // W2t
    int o = bid * 256 + t;
    if (o < 512 * 48) {
      int col = o / 48, c4 = (o - col * 48) * 4;
      int hh = col >> 6, d = col & 63;
      ushort4 v;
      v.x = (c4 + 0 < 133) ? f2b(P.Whd[(hh * 133 + c4 + 0) * 64 + d]) : (ushort_t)0;
      v.y = (c4 + 1 < 133) ? f2b(P.Whd[(hh * 133 + c4 + 1) * 64 + d]) : (ushort_t)0;
      v.z = (c4 + 2 < 133) ? f2b(P.Whd[(hh * 133 + c4 + 2) * 64 + d]) : (ushort_t)0;
      v.w = (c4 + 3 < 133) ? f2b(P.Whd[(hh * 133 + c4 + 3) * 64 + d]) : (ushort_t)0;
      *(ushort4*)&P.W2t[(size_t)col * KP1 + c4] = v;
    }
    return;
  }
  bid -= 96;
  if (bid < 768) {  // fpb
    int o = bid * 256 + t;
    int row = o / 384, c4 = (o - row * 384) * 4;
    const float* fr = P.fp + (size_t)row * 1489;
    ushort4 v;
    v.x = (c4 + 0 < 1489) ? f2b(fr[c4 + 0]) : (ushort_t)0;
    v.y = (c4 + 1 < 1489) ? f2b(fr[c4 + 1]) : (ushort_t)0;
    v.z = (c4 + 2 < 1489) ? f2b(fr[c4 + 2]) : (ushort_t)0;
    v.w = (c4 + 3 < 1489) ? f2b(fr[c4 + 3]) : (ushort_t)0;
    *(ushort4*)&P.fpb[(size_t)row * KPF + c4] = v;
    return;
  }
  bid -= 768;
  if (bid < 768) {  // fc1t (transpose K=1489 N=512 Kpad=1536)
    int o = bid * 256 + t;
    int col = o / 384, k4 = (o - col * 384) * 4;
    ushort4 v;
    v.x = (k4 + 0 < 1489) ? f2b(P.fc1_w[(size_t)(k4 + 0) * 512 + col]) : (ushort_t)0;
    v.y = (k4 + 1 < 1489) ? f2b(P.fc1_w[(size_t)(k4 + 1) * 512 + col]) : (ushort_t)0;
    v.z = (k4 + 2 < 1489) ? f2b(P.fc1_w[(size_t)(k4 + 2) * 512 + col]) : (ushort_t)0;
    v.w = (k4 + 3 < 1489) ? f2b(P.fc1_w[(size_t)(k4 + 3) * 512 + col]) : (ushort_t)0;
    *(ushort4*)&P.fc1t[(size_t)col * KPF + k4] = v;
    return;
  }
  bid -= 768;
  if (bid < 1536) {  // 6x 512x512 transposes
    int y = bid >> 8;
    int o = (bid & 255) * 256 + t;
    const float* W = y == 0 ? P.W_out : y == 1 ? P.fc2_w : y == 2 ? P.q_w
                   : y == 3 ? P.v_w : y == 4 ? P.o_w : P.ffn1_w;
    ushort_t* Wt = y == 0 ? P.Wot : y == 1 ? P.fc2t : y == 2 ? P.qwt
                 : y == 3 ? P.vwt : y == 4 ? P.owt : P.f1t;
    int col = o >> 7, k4 = (o & 127) * 4;
    ushort4 v;
    v.x = f2b(W[(size_t)(k4 + 0) * 512 + col]);
    v.y = f2b(W[(size_t)(k4 + 1) * 512 + col]);
    v.z = f2b(W[(size_t)(k4 + 2) * 512 + col]);
    v.w = f2b(W[(size_t)(k4 + 3) * 512 + col]);
    *(ushort4*)&Wt[(size_t)col * 512 + k4] = v;
    return;
  }
  bid -= 1536;
  if (bid < 12288) {  // hb
    int o = bid * 256 + t;
    int row = o / 48, c4 = (o - row * 48) * 4;
    const float* hr = P.h + (size_t)row * 133;
    ushort4 v;
    v.x = (c4 + 0 < 133) ? f2b(hr[c4 + 0]) : (ushort_t)0;
    v.y = (c4 + 1 < 133) ? f2b(hr[c4 + 1]) : (ushort_t)0;
    v.z = (c4 + 2 < 133) ? f2b(hr[c4 + 2]) : (ushort_t)0;
    v.w = (c4 + 3 < 133) ? f2b(hr[c4 + 3]) : (ushort_t)0;
    *(ushort4*)&P.hb[(size_t)row * KP1 + c4] = v;
    return;
  }
  bid -= 12288;
  {  // em
    size_t o = ((size_t)bid * 256 + t) * 4;
    float4 e = *(const float4*)&P.edge[o];
    int4 a = *(const int4*)&P.adj[o];
    ushort4 v;
    v.x = a.x > 0 ? f2b(e.x) : (ushort_t)MINF_BF16;
    v.y = a.y > 0 ? f2b(e.y) : (ushort_t)MINF_BF16;
    v.z = a.z > 0 ? f2b(e.z) : (ushort_t)MINF_BF16;
    v.w = a.w > 0 ? f2b(e.w) : (ushort_t)MINF_BF16;
    *(ushort4*)&P.em[o] = v;
  }
}

// ---------------------------------------------------------------------------
// GAT layer 1 body. id in [0, 8*C): xcd=id&7, head=(id>>3)&7,
// bl=((id>>6)<<3)|(id&7). s1/s2 ride the MFMA via wh12 B-columns.
__device__ void gat1_body(int id, int base, const MP& P, LdsGat1& L) {
  const int hh = (id >> 3) & 7;
  const int bl = ((id >> 6) << 3) | (id & 7);
  const int bg = base + bl;
  const int t = threadIdx.x;
  const int lane = t & 63, w = t >> 6;
  const int l16 = lane & 15, quad = lane >> 4;
  const int w8 = w * 8, sr8 = (t >> 3) & 7;
  const int csw = ((t & 7) ^ sr8) << 3;  // pre-swizzled source column

  if (t < 96)
    *(ushort4*)&(&L.wh12s[0][0])[t * 4] =
        *(const ushort4*)&P.wh12[hh * 384 + t * 4];

  const ushort_t* gA = P.hb + (size_t)(bg * 128 + w8 + sr8) * KP1 + csw;
  const ushort_t* gB = P.W2t + (size_t)(hh * 64 + w8 + sr8) * KP1 + csw;
  ffrag acc[2][4];
  ffrag acc_s[2];
#pragma unroll
  for (int mi = 0; mi < 2; ++mi) {
    acc_s[mi] = {0.f, 0.f, 0.f, 0.f};
#pragma unroll
    for (int ni = 0; ni < 4; ++ni) acc[mi][ni] = {0.f, 0.f, 0.f, 0.f};
  }
  for (int k0 = 0; k0 < KP1; k0 += 64) {
    __syncthreads();
#pragma unroll
    for (int p = 0; p < 4; ++p)
      gll16(gA + (size_t)(p * 32) * KP1 + k0, &L.u.g.As[p * 32 + w8][0]);
#pragma unroll
    for (int p = 0; p < 2; ++p)
      gll16(gB + (size_t)(p * 32) * KP1 + k0, &L.u.g.Bs[p * 32 + w8][0]);
    __syncthreads();
#pragma unroll
    for (int ks = 0; ks < 2; ++ks) {
      const int cs = ((ks * 4 + quad) ^ (l16 & 7)) << 3;  // swizzled read
      bfrag af[2], bf[4];
      bfrag bs = {0, 0, 0, 0, 0, 0, 0, 0};
      if (l16 < 2)
        bs = *(const bfrag*)&L.wh12s[l16][k0 + ks * 32 + quad * 8];
#pragma unroll
      for (int mi = 0; mi < 2; ++mi)
        af[mi] = *(const bfrag*)&L.u.g.As[w * 32 + mi * 16 + l16][cs];
#pragma unroll
      for (int ni = 0; ni < 4; ++ni)
        bf[ni] = *(const bfrag*)&L.u.g.Bs[ni * 16 + l16][cs];
#pragma unroll
      for (int mi = 0; mi < 2; ++mi) {
#pragma unroll
        for (int ni = 0; ni < 4; ++ni)
          acc[mi][ni] = __builtin_amdgcn_mfma_f32_16x16x32_bf16(
              af[mi], bf[ni], acc[mi][ni], 0, 0, 0);
        acc_s[mi] = __builtin_amdgcn_mfma_f32_16x16x32_bf16(
            af[mi], bs, acc_s[mi], 0, 0, 0);
      }
    }
  }
  __syncthreads();  // staging dead; LDS becomes WS

#pragma unroll
  for (int mi = 0; mi < 2; ++mi)
#pragma unroll
    for (int ni = 0; ni < 4; ++ni) {
      int col = ni * 16 + l16;
      int rowb = w * 32 + mi * 16 + quad * 4;
      uint2 pv;
      pv.x = cvt_pk(acc[mi][ni][0], acc[mi][ni][1]);
      pv.y = cvt_pk(acc[mi][ni][2], acc[mi][ni][3]);
      *(uint2*)&L.u.WS[col][rowb] = pv;
    }
  if (l16 < 2) {
    float* sp = (l16 == 0) ? L.ss1 : L.ss2;
#pragma unroll
    for (int mi = 0; mi < 2; ++mi)
#pragma unroll
      for (int r = 0; r < 4; ++r)
        sp[w * 32 + mi * 16 + quad * 4 + r] = acc_s[mi][r] * LOG2E;
  }
  uint4 ereg[2][4];
  {
    const ushort_t* em = P.em + (size_t)bg * 16384;
#pragma unroll
    for (int mi = 0; mi < 2; ++mi) {
      int row = w * 32 + mi * 16 + l16;
#pragma unroll
      for (int ks = 0; ks < 4; ++ks)
        ereg[mi][ks] = *(const uint4*)&em[row * 128 + ks * 32 + quad * 8];
    }
  }
  __syncthreads();

  const float aeh2 = P.aeh[hh] * LOG2E;
  float rs1[2];
  rs1[0] = L.ss1[w * 32 + l16];
  rs1[1] = L.ss1[w * 32 + 16 + l16];
  uint4 aw[2][4];
#pragma unroll
  for (int mi = 0; mi < 2; ++mi) {
#pragma unroll
    for (int ks = 0; ks < 4; ++ks) {
      float s2v[8];
      *(float4*)&s2v[0] = *(const float4*)&L.ss2[ks * 32 + quad * 8];
      *(float4*)&s2v[4] = *(const float4*)&L.ss2[ks * 32 + quad * 8 + 4];
      const unsigned uu[4] = {ereg[mi][ks].x, ereg[mi][ks].y,
                              ereg[mi][ks].z, ereg[mi][ks].w};
      unsigned po[4];
#pragma unroll
      for (int pr = 0; pr < 4; ++pr) {
        float elo = __uint_as_float(uu[pr] << 16);
        float ehi = __uint_as_float(uu[pr] & 0xffff0000u);
        float e0 = fmaf(elo, aeh2, rs1[mi] + s2v[pr * 2]);
        float e1 = fmaf(ehi, aeh2, rs1[mi] + s2v[pr * 2 + 1]);
        e0 = fmaxf(e0, ALPHA_LK * e0);
        e1 = fmaxf(e1, ALPHA_LK * e1);
        float p0 = (elo != -INFINITY) ? fexp2(e0) : 0.f;
        float p1 = (ehi != -INFINITY) ? fexp2(e1) : 0.f;
        po[pr] = cvt_pk(p0, p1);
      }
      aw[mi][ks] = make_uint4(po[0], po[1], po[2], po[3]);
    }
  }

  bfrag bones;
#pragma unroll
  for (int i = 0; i < 8; ++i) bones[i] = (short)0x3F80;

  ffrag acc2[2][4];
  ffrag accs[2];
#pragma unroll
  for (int mi = 0; mi < 2; ++mi) {
    accs[mi] = {0.f, 0.f, 0.f, 0.f};
#pragma unroll
    for (int ni = 0; ni < 4; ++ni) acc2[mi][ni] = {0.f, 0.f, 0.f, 0.f};
  }
#pragma unroll
  for (int ks = 0; ks < 4; ++ks) {
    bfrag bfr[4];
#pragma unroll
    for (int ni = 0; ni < 4; ++ni)
      bfr[ni] = *(const bfrag*)&L.u.WS[ni * 16 + l16][ks * 32 + quad * 8];
#pragma unroll
    for (int mi = 0; mi < 2; ++mi) {
      bfrag afr;
      __builtin_memcpy(&afr, &aw[mi][ks], 16);
#pragma unroll
      for (int ni = 0; ni < 4; ++ni)
        acc2[mi][ni] = __builtin_amdgcn_mfma_f32_16x16x32_bf16(
            afr, bfr[ni], acc2[mi][ni], 0, 0, 0);
      accs[mi] = __builtin_amdgcn_mfma_f32_16x16x32_bf16(
          afr, bones, accs[mi], 0, 0, 0);
    }
  }
  float sv[2][4];
#pragma unroll
  for (int mi = 0; mi < 2; ++mi)
#pragma unroll
    for (int r = 0; r < 4; ++r)
      sv[mi][r] = frcp(fmaxf(accs[mi][r], 1e-30f));

#pragma unroll
  for (int mi = 0; mi < 2; ++mi)
#pragma unroll
    for (int ni = 0; ni < 4; ++ni) {
      float e0 = elu1(acc2[mi][ni][0] * sv[mi][0]);
      float e1 = elu1(acc2[mi][ni][1] * sv[mi][1]);
      float e2 = elu1(acc2[mi][ni][2] * sv[mi][2]);
      float e3 = elu1(acc2[mi][ni][3] * sv[mi][3]);
      unsigned p01 = cvt_pk(e0, e1), p23 = cvt_pk(e2, e3);
      int rl = w * 32 + mi * 16 + quad * 4;
      size_t bo = (size_t)(bl * 128 + rl) * 512 + hh * 64 + ni * 16 + l16;
      P.xb[bo] = (ushort_t)p01;
      P.xb[bo + 512] = (ushort_t)(p01 >> 16);
      P.xb[bo + 1024] = (ushort_t)p23;
      P.xb[bo + 1536] = (ushort_t)(p23 >> 16);
    }
}

// ---------------------------------------------------------------------------
// att2t body: t1/t2 (2 thr/row, wa in LDS) then softmax -> aw bf16 + sinv.
__device__ void att2t_body(int bl, int base, const MP& P, LdsAtt& L) {
  const int bg = base + bl;
  const int t = threadIdx.x;
  L.was1[t] = P.wa1[t]; L.was1[t + 256] = P.wa1[t + 256];
  L.was2[t] = P.wa2[t]; L.was2[t + 256] = P.wa2[t + 256];
  __syncthreads();
  const int row = t >> 1, half = t & 1;
  {
    const ushort_t* xr = P.xb + (size_t)(bl * 128 + row) * 512 + half * 256;
    float p1 = 0.f, p2 = 0.f;
#pragma unroll 4
    for (int i = 0; i < 32; ++i) {
      uint4 u = *(const uint4*)&xr[i * 8];
      const unsigned uu[4] = {u.x, u.y, u.z, u.w};
#pragma unroll
      for (int pr = 0; pr < 4; ++pr) {
        float lo = __uint_as_float(uu[pr] << 16);
        float hi = __uint_as_float(uu[pr] & 0xffff0000u);
        int c = half * 256 + i * 8 + pr * 2;
        p1 = fmaf(lo, L.was1[c], p1); p1 = fmaf(hi, L.was1[c + 1], p1);
        p2 = fmaf(lo, L.was2[c], p2); p2 = fmaf(hi, L.was2[c + 1], p2);
      }
    }
    p1 += __shfl_xor(p1, 1);
    p2 += __shfl_xor(p2, 1);
    if (!half) { L.t1s[row] = p1 * LOG2E; L.t2s[row] = p2 * LOG2E; }
  }
  __syncthreads();
  const float ae2 = P.aeo[0] * LOG2E;
  const float rt1 = L.t1s[row];
  const ushort_t* emr = P.em + (size_t)bg * 16384 + row * 128 + half * 64;
  ushort_t* awr = P.awg + (size_t)bl * 16384 + row * 128 + half * 64;
  float s = 0.f;
#pragma unroll
  for (int v = 0; v < 8; ++v) {
    uint4 eu = *(const uint4*)&emr[v * 8];
    const unsigned uu[4] = {eu.x, eu.y, eu.z, eu.w};
    unsigned po[4];
#pragma unroll
    for (int pr = 0; pr < 4; ++pr) {
      float elo = __uint_as_float(uu[pr] << 16);
      float ehi = __uint_as_float(uu[pr] & 0xffff0000u);
      float e0 = fmaf(elo, ae2, rt1 + L.t2s[half * 64 + v * 8 + pr * 2]);
      float e1 = fmaf(ehi, ae2, rt1 + L.t2s[half * 64 + v * 8 + pr * 2 + 1]);
      e0 = fmaxf(e0, ALPHA_LK * e0);
      e1 = fmaxf(e1, ALPHA_LK * e1);
      float p0 = (elo != -INFINITY) ? fexp2(e0) : 0.f;
      float p1 = (ehi != -INFINITY) ? fexp2(e1) : 0.f;
      unsigned q = cvt_pk(p0, p1);
      po[pr] = q;
      s += __uint_as_float(q << 16) + __uint_as_float(q & 0xffff0000u);
    }
    *(uint4*)&awr[v * 8] = make_uint4(po[0], po[1], po[2], po[3]);
  }
  s += __shfl_xor(s, 1);
  if (!half) P.sinv[(size_t)bl * 128 + row] = 1.f / fmaxf(s, 1e-30f);
}

// ---------------------------------------------------------------------------
// GAT output layer body. id in [0, 4*C): xcd=id&7, sp2=(id>>3)&3,
// bl=((id>>5)<<3)|(id&7).
__device__ void gat2_body(int id, int base, const MP& P, LdsGat2& L) {
  const int sp2 = (id >> 3) & 3;
  const int bl = ((id >> 5) << 3) | (id & 7);
  const int bg = base + bl;
  const int t = threadIdx.x;
  const int lane = t & 63, w = t >> 6;
  const int wm = w >> 1, wn = w & 1;
  const int l16 = lane & 15, quad = lane >> 4;
  const int w8 = w * 8, sr8 = (t >> 3) & 7;
  const int csw = ((t & 7) ^ sr8) << 3;

  const ushort_t* gA = P.xb + (size_t)(bl * 128 + w8 + sr8) * 512 + csw;
  const ushort_t* gB = P.Wot + (size_t)(sp2 * 128 + w8 + sr8) * 512 + csw;
  ffrag acc[4][4];
#pragma unroll
  for (int mi = 0; mi < 4; ++mi)
#pragma unroll
    for (int ni = 0; ni < 4; ++ni) acc[mi][ni] = {0.f, 0.f, 0.f, 0.f};
  for (int k0 = 0; k0 < 512; k0 += 64) {
    __syncthreads();
#pragma unroll
    for (int p = 0; p < 4; ++p) {
      gll16(gA + (size_t)(p * 32) * 512 + k0, &L.u.g.As[p * 32 + w8][0]);
      gll16(gB + (size_t)(p * 32) * 512 + k0, &L.u.g.Bs[p * 32 + w8][0]);
    }
    __syncthreads();
#pragma unroll
    for (int ks = 0; ks < 2; ++ks) {
      const int cs = ((ks * 4 + quad) ^ (l16 & 7)) << 3;
      bfrag af[4], bf[4];
#pragma unroll
      for (int i = 0; i < 4; ++i) {
        af[i] = *(const bfrag*)&L.u.g.As[wm * 64 + i * 16 + l16][cs];
        bf[i] = *(const bfrag*)&L.u.g.Bs[wn * 64 + i * 16 + l16][cs];
      }
#pragma unroll
      for (int mi = 0; mi < 4; ++mi)
#pragma unroll
        for (int ni = 0; ni < 4; ++ni)
          acc[mi][ni] = __builtin_amdgcn_mfma_f32_16x16x32_bf16(
              af[mi], bf[ni], acc[mi][ni], 0, 0, 0);
    }
  }
  __syncthreads();

#pragma unroll
  for (int mi = 0; mi < 4; ++mi)
#pragma unroll
    for (int ni = 0; ni < 4; ++ni) {
      int col = wn * 64 + ni * 16 + l16;
      int rowb = wm * 64 + mi * 16 + quad * 4;
      uint2 pv;
      pv.x = cvt_pk(acc[mi][ni][0], acc[mi][ni][1]);
      pv.y = cvt_pk(acc[mi][ni][2], acc[mi][ni][3]);
      *(uint2*)&L.u.WS[col][rowb] = pv;
    }
  __syncthreads();

  uint4 awf[2][4];
  float sv[2][4];
  {
    const ushort_t* ap = P.awg + (size_t)bl * 16384;
#pragma unroll
    for (int mi = 0; mi < 2; ++mi) {
      int row = w * 32 + mi * 16 + l16;
#pragma unroll
      for (int ks = 0; ks < 4; ++ks)
        awf[mi][ks] = *(const uint4*)&ap[row * 128 + ks * 32 + quad * 8];
      float si = P.sinv[(size_t)bl * 128 + row];
#pragma unroll
      for (int r = 0; r < 4; ++r) sv[mi][r] = __shfl(si, quad * 4 + r);
    }
  }

  for (int s0 = 0; s0 < 2; ++s0) {
    ffrag acc2[2][4];
#pragma unroll
    for (int mi = 0; mi < 2; ++mi)
#pragma unroll
      for (int ni = 0; ni < 4; ++ni) acc2[mi][ni] = {0.f, 0.f, 0.f, 0.f};
#pragma unroll
    for (int ks = 0; ks < 4; ++ks) {
      bfrag bfr[4];
#pragma unroll
      for (int ni = 0; ni < 4; ++ni)
        bfr[ni] = *(const bfrag*)&L.u.WS[s0 * 64 + ni * 16 + l16][ks * 32 + quad * 8];
#pragma unroll
      for (int mi = 0; mi < 2; ++mi) {
        bfrag afr;
        __builtin_memcpy(&afr, &awf[mi][ks], 16);
#pragma unroll
        for (int ni = 0; ni < 4; ++ni)
          acc2[mi][ni] = __builtin_amdgcn_mfma_f32_16x16x32_bf16(
              afr, bfr[ni], acc2[mi][ni], 0, 0, 0);
      }
    }
    __syncthreads();
#pragma unroll
    for (int ni = 0; ni < 4; ++ni) {
      float s = 0.f;
#pragma unroll
      for (int mi = 0; mi < 2; ++mi)
#pragma unroll
        for (int r = 0; r < 4; ++r) s += elu1(acc2[mi][ni][r] * sv[mi][r]);
      s += __shfl_xor(s, 16);
      s += __shfl_xor(s, 32);
      if (quad == 0) L.ps[w][ni * 16 + l16] = s;
    }
    __syncthreads();
    if (t < 64) {
      float s = L.ps[0][t] + L.ps[1][t] + L.ps[2][t] + L.ps[3][t];
      P.gatb[(size_t)bg * 512 + sp2 * 128 + s0 * 64 + t] = f2b(s * (1.f / 128.f));
    }
  }
}

// ---------------------------------------------------------------------------
__device__ void tail_kloop(const ushort_t* A, const ushort_t* Bt, int K, int ld,
                           ushort_t (*As)[64], ushort_t (*Bs)[64],
                           ffrag (*acc)[4], int row0, int col0, int t) {
  const int lane = t & 63, w = t >> 6;
  const int wm = w >> 1, wn = w & 1;
  const int l16 = lane & 15, quad = lane >> 4;
  const int w8 = w * 8, sr8 = (t >> 3) & 7;
  const int csw = ((t & 7) ^ sr8) << 3;
  const ushort_t* gA = A + (size_t)(row0 + w8 + sr8) * ld + csw;
  const ushort_t* gB = Bt + (size_t)(col0 + w8 + sr8) * ld + csw;
  for (int k0 = 0; k0 < K; k0 += 64) {
    __syncthreads();
#pragma unroll
    for (int p = 0; p < 4; ++p) {
      gll16(gA + (size_t)(p * 32) * ld + k0, &As[p * 32 + w8][0]);
      gll16(gB + (size_t)(p * 32) * ld + k0, &Bs[p * 32 + w8][0]);
    }
    __syncthreads();
#pragma unroll
    for (int ks = 0; ks < 2; ++ks) {
      const int cs = ((ks * 4 + quad) ^ (l16 & 7)) << 3;
      bfrag af[4], bf[4];
#pragma unroll
      for (int i = 0; i < 4; ++i) {
        af[i] = *(const bfrag*)&As[wm * 64 + i * 16 + l16][cs];
        bf[i] = *(const bfrag*)&Bs[wn * 64 + i * 16 + l16][cs];
      }
#pragma unroll
      for (int mi = 0; mi < 4; ++mi)
#pragma unroll
        for (int ni = 0; ni < 4; ++ni)
          acc[mi][ni] = __builtin_amdgcn_mfma_f32_16x16x32_bf16(
              af[mi], bf[ni], acc[mi][ni], 0, 0, 0);
    }
  }
}

// one 128x128 tile of C = act(A1@Bt1^T (+A2@Bt2^T) + bias). vb in [0,16).
__device__ void tailg_body(int vb, const ushort_t* A1, const ushort_t* Bt1,
                           int K1, int ld1, const ushort_t* A2,
                           const ushort_t* Bt2, const float* bias,
                           ushort_t* Cc, int DUAL, int RELU, LdsTail& L) {
  const int t = threadIdx.x;
  const int lane = t & 63, w = t >> 6;
  const int wm = w >> 1, wn = w & 1;
  const int l16 = lane & 15, quad = lane >> 4;
  const int row0 = (vb >> 2) * 128, col0 = (vb & 3) * 128;

  ffrag acc[4][4];
#pragma unroll
  for (int mi = 0; mi < 4; ++mi)
#pragma unroll
    for (int ni = 0; ni < 4; ++ni) acc[mi][ni] = {0.f, 0.f, 0.f, 0.f};

  tail_kloop(A1, Bt1, K1, ld1, L.As, L.Bs, acc, row0, col0, t);
  if (DUAL) tail_kloop(A2, Bt2, 512, 512, L.As, L.Bs, acc, row0, col0, t);

#pragma unroll
  for (int mi = 0; mi < 4; ++mi)
#pragma unroll
    for (int ni = 0; ni < 4; ++ni) {
      int col = col0 + wn * 64 + ni * 16 + l16;
      float bb = bias[col];
      float v0 = acc[mi][ni][0] + bb, v1 = acc[mi][ni][1] + bb;
      float v2 = acc[mi][ni][2] + bb, v3 = acc[mi][ni][3] + bb;
      if (RELU) {
        v0 = fmaxf(v0, 0.f); v1 = fmaxf(v1, 0.f);
        v2 = fmaxf(v2, 0.f); v3 = fmaxf(v3, 0.f);
      }
      unsigned p01 = cvt_pk(v0, v1), p23 = cvt_pk(v2, v3);
      int row = row0 + wm * 64 + mi * 16 + quad * 4;
      size_t o = (size_t)row * 512 + col;
      Cc[o] = (ushort_t)p01;
      Cc[o + 512] = (ushort_t)(p01 >> 16);
      Cc[o + 1024] = (ushort_t)p23;
      Cc[o + 1536] = (ushort_t)(p23 >> 16);
    }
}

// out[512][12] = fb5 @ ffn2_w + b. vb in [0,128), 4 rows per vb.
__device__ void ffn2_body(int vb, const MP& P) {
  int wv = threadIdx.x >> 6, lane = threadIdx.x & 63;
  int row = vb * 4 + wv;
  const ushort_t* fr = P.fb5 + (size_t)row * 512;
  float v[8];
  ushort4 u0 = *(const ushort4*)&fr[lane * 8];
  ushort4 u1 = *(const ushort4*)&fr[lane * 8 + 4];
  v[0] = b2f(u0.x); v[1] = b2f(u0.y); v[2] = b2f(u0.z); v[3] = b2f(u0.w);
  v[4] = b2f(u1.x); v[5] = b2f(u1.y); v[6] = b2f(u1.z); v[7] = b2f(u1.w);
#pragma unroll
  for (int j = 0; j < 12; ++j) {
    float s = 0.f;
#pragma unroll
    for (int i = 0; i < 8; ++i)
      s += v[i] * P.ffn2_w[(size_t)(lane * 8 + i) * 12 + j];
#pragma unroll
    for (int off = 32; off; off >>= 1) s += __shfl_down(s, off);
    if (lane == 0) P.out[(size_t)row * 12 + j] = s + P.ffn2_b[j];
  }
}

// ---------------------------------------------------------------------------
__global__ __launch_bounds__(256) void k_prep(MP P) { prep_body(blockIdx.x, P); }

__global__ __launch_bounds__(256) void k_gat1(MP P, int base) {
  __shared__ LdsGat1 L;
  gat1_body(blockIdx.x, base, P, L);
}

// att2t launch; last 16 blocks (base==0 only) compute fb1 tiles.
__global__ __launch_bounds__(256) void k_att(MP P, int base) {
  __shared__ union { LdsAtt at; LdsTail tl; } L;
  int b = blockIdx.x;
  if (b < P.C) att2t_body(b, base, P, L.at);
  else tailg_body(b - P.C, P.fpb, P.fc1t, KPF, KPF, nullptr, nullptr,
                  P.fc1_b, P.fb1, 0, 1, L.tl);
}

// gat2 launch; last 16 blocks (base==0 only) compute fb2 tiles.
__global__ __launch_bounds__(256) void k_gat2(MP P, int base) {
  __shared__ union { LdsGat2 g2; LdsTail tl; } L;
  int b = blockIdx.x;
  if (b < 4 * P.C) gat2_body(b, base, P, L.g2);
  else tailg_body(b - 4 * P.C, P.fb1, P.fc2t, 512, 512, nullptr, nullptr,
                  P.fc2_b, P.fb2, 0, 0, L.tl);
}

__global__ __launch_bounds__(256) void k_tail(MP P, int stage) {
  __shared__ LdsTail L;
  int vb = blockIdx.x;
  if (stage == 2)      tailg_body(vb, P.gatb, P.qwt, 512, 512, P.fb2, P.vwt, P.qvb, P.fb3, 1, 0, L);
  else if (stage == 3) tailg_body(vb, P.fb3, P.owt, 512, 512, nullptr, nullptr, P.o_b, P.fb4, 0, 1, L);
  else                 tailg_body(vb, P.fb4, P.f1t, 512, 512, nullptr, nullptr, P.ffn1_b, P.fb5, 0, 1, L);
}
__global__ __launch_bounds__(256) void k_ffn2(MP P) { ffn2_body(blockIdx.x, P); }

// ---------------------------------------------------------------------------
extern "C" void kernel_launch(void* const* d_in, const int* in_sizes, int n_in,
                              void* d_out, int out_size, void* d_ws, size_t ws_size,
                              hipStream_t stream) {
  MP P;
  P.h        = (const float*)d_in[0];
  P.adj      = (const int*)d_in[1];
  P.edge     = (const float*)d_in[2];
  P.fp       = (const float*)d_in[3];
  P.Whd      = (const float*)d_in[4];
  P.a1h      = (const float*)d_in[5];
  P.a2h      = (const float*)d_in[6];
  P.aeh      = (const float*)d_in[7];
  P.W_out    = (const float*)d_in[8];
  P.a1o      = (const float*)d_in[9];
  P.a2o      = (const float*)d_in[10];
  P.aeo      = (const float*)d_in[11];
  P.fc1_w    = (const float*)d_in[12];
  P.fc1_b    = (const float*)d_in[13];
  P.fc2_w    = (const float*)d_in[14];
  P.fc2_b    = (const float*)d_in[15];
  P.q_w      = (const float*)d_in[16];
  P.q_b      = (const float*)d_in[17];
  // k_w/k_b (18,19) dead: softmax over size-1 axis == 1 => fused = q + v
  P.v_w      = (const float*)d_in[20];
  P.v_b      = (const float*)d_in[21];
  P.o_w      = (const float*)d_in[22];
  P.o_b      = (const float*)d_in[23];
  P.ffn1_w   = (const float*)d_in[24];
  P.ffn1_b   = (const float*)d_in[25];
  P.ffn2_w   = (const float*)d_in[26];
  P.ffn2_b   = (const float*)d_in[27];
  P.out      = (float*)d_out;

  // ---- workspace carve (R5 layout) ----
  const size_t hb_bytes = (size_t)65536 * KP1 * 2;
  const size_t em_bytes = (size_t)512 * 16384 * 2;
  const size_t tail_bytes =
      (size_t)512 * KPF * 2 * 2 + (size_t)512 * 512 * 2 * 12 + 2048;
  const size_t fixed_bytes = hb_bytes + em_bytes + (size_t)512 * KP1 * 2 +
                             (size_t)2 * 65536 * 4 + tail_bytes + 16384;
  int C = 32;
  for (int cand = 512; cand >= 32; cand >>= 1) {
    size_t need = (size_t)cand * (131072 + 32768 + 512) + fixed_bytes;
    if (need <= ws_size) { C = cand; break; }
  }
  P.C = C;

  char* p = (char*)d_ws;
  P.xb  = (ushort_t*)p; p += (size_t)C * 65536 * 2;
  P.awg = (ushort_t*)p; p += (size_t)C * 16384 * 2;
  P.sinv = (float*)p;   p += (size_t)C * 128 * 4;
  P.hb  = (ushort_t*)p; p += hb_bytes;
  P.em  = (ushort_t*)p; p += em_bytes;
  P.W2t = (ushort_t*)p; p += (size_t)512 * KP1 * 2;
  P.wh12 = (ushort_t*)p; p += 8 * 384 * 2;
  p += 2 * 65536 * 4 - 8 * 384 * 2;
  P.fpb  = (ushort_t*)p; p += (size_t)512 * KPF * 2;
  P.fc1t = (ushort_t*)p; p += (size_t)512 * KPF * 2;
  P.Wot  = (ushort_t*)p; p += (size_t)512 * 512 * 2;
  P.fc2t = (ushort_t*)p; p += (size_t)512 * 512 * 2;
  P.qwt  = (ushort_t*)p; p += (size_t)512 * 512 * 2;
  P.vwt  = (ushort_t*)p; p += (size_t)512 * 512 * 2;
  P.owt  = (ushort_t*)p; p += (size_t)512 * 512 * 2;
  P.f1t  = (ushort_t*)p; p += (size_t)512 * 512 * 2;
  P.gatb = (ushort_t*)p; p += (size_t)512 * 512 * 2;
  P.fb1  = (ushort_t*)p; p += (size_t)512 * 512 * 2;
  P.fb2  = (ushort_t*)p; p += (size_t)512 * 512 * 2;
  P.fb3  = (ushort_t*)p; p += (size_t)512 * 512 * 2;
  P.fb4  = (ushort_t*)p; p += (size_t)512 * 512 * 2;
  P.fb5  = (ushort_t*)p; p += (size_t)512 * 512 * 2;
  P.qvb  = (float*)p; p += 2048;
  P.wa1  = (float*)p; p += 2048;
  P.wa2  = (float*)p; p += 2048;

  // 8 dispatches total (C=512 case)
  k_prep<<<23786, 256, 0, stream>>>(P);
  for (int base = 0; base < 512; base += C) {
    int r = (base == 0) ? 16 : 0;
    k_gat1<<<8 * C, 256, 0, stream>>>(P, base);
    k_att<<<C + r, 256, 0, stream>>>(P, base);
    k_gat2<<<4 * C + r, 256, 0, stream>>>(P, base);
  }
  k_tail<<<16, 256, 0, stream>>>(P, 2);
  k_tail<<<16, 256, 0, stream>>>(P, 3);
  k_tail<<<16, 256, 0, stream>>>(P, 4);
  k_ffn2<<<128, 256, 0, stream>>>(P);
}

// Round 10
// 423.669 us; speedup vs baseline: 1.3809x; 1.1511x over previous
//
#include <hip/hip_runtime.h>
#include <hip/hip_bf16.h>

// FPGNN forward for MI355X. Round 22 == Round 17/R5 verbatim (426.06 us,
// best verified). R9's post-mortem: the MP-struct + LDS-union refactor
// regressed gat2 63->108 us via a 20x LDS bank-conflict explosion
// (1.57e6 -> 3.2e7) -- hot MFMA kernels need direct __restrict__ args and
// locally-declared __shared__. Reverting to the proven source.
//  (1) 7 preamble kernels -> 1 prep_all (blockIdx-range segmented).
//  (2) t12x folded into att2 -> att2t (1 block/graph, t-phase + softmax).
//  (3) gat1: s1/s2 via MFMA wh12 B-columns (serial dot loop deleted).
// Shapes: B=512, N=128, F_IN=133, NHEADS=8, NHID=64, HID=512, FP_DIM=1489, TASKS=12

#define ALPHA_LK 0.2f
#define LOG2E 1.44269504f
#define KP1 192   // F_IN=133 padded to 3*64
#define KPF 1536  // FP_DIM=1489 padded to 24*64
#define MINF_BF16 0xFF80u

typedef unsigned short ushort_t;
typedef __attribute__((ext_vector_type(8))) short bfrag;   // 8 x bf16 (4 VGPRs)
typedef __attribute__((ext_vector_type(4))) float ffrag;   // 4 x f32 acc

__device__ __forceinline__ float b2f(ushort_t u) {
  return __uint_as_float(((unsigned)u) << 16);
}
__device__ __forceinline__ ushort_t f2b(float f) {
  unsigned u = __float_as_uint(f);
  unsigned r = (u + 0x7fffu + ((u >> 16) & 1u)) >> 16;  // RNE
  return (ushort_t)r;
}
// packed 2xf32 -> 2xbf16 (RNE), 1 instruction
__device__ __forceinline__ unsigned cvt_pk(float lo, float hi) {
  unsigned r;
  asm("v_cvt_pk_bf16_f32 %0, %1, %2" : "=v"(r) : "v"(lo), "v"(hi));
  return r;
}
__device__ __forceinline__ float frcp(float x) {
  float r;
  asm("v_rcp_f32 %0, %1" : "=v"(r) : "v"(x));
  return r;
}
__device__ __forceinline__ float fexp2(float x) {
#if __has_builtin(__builtin_amdgcn_exp2f)
  return __builtin_amdgcn_exp2f(x);
#else
  return exp2f(x);
#endif
}
__device__ __forceinline__ float elu1(float v) {
  return v > 0.f ? v : __expf(v) - 1.f;
}

// direct global->LDS, 16 B per lane. LDS dest = wave-uniform base + lane*16.
__device__ __forceinline__ void gll16(const void* g, void* l) {
  __builtin_amdgcn_global_load_lds(
      (const __attribute__((address_space(1))) unsigned int*)(unsigned long long)g,
      (__attribute__((address_space(3))) unsigned int*)(unsigned long long)l,
      16, 0, 0);
}

// ---------------------------------------------------------------------------
// prep_all: all preamble work in one launch, segmented by blockIdx.x.
//  [0,8)       wh12: wh1/wh2[h][f] = sum_d W_heads[h,f,d]*a1/a2[h,d]
//  [8,136)     wa12: wa1/wa2 = W_out @ a1_out / a2_out
//  [136,138)   qvb = q_b + v_b
//  [138,234)   W_heads -> W2t bf16 [512][192]
//  [234,1002)  fp -> fpb bf16 [512][1536]
//  [1002,1770) fc1_w -> fc1t (transpose, Kpad=1536)
//  [1770,3306) 6x 512x512 transpose f32->bf16
//  [3306,15594) h -> hb bf16 [65536][192]
//  [15594,23786) edge/adj -> em bf16 masked
__global__ __launch_bounds__(256) void prep_all(
    const float* __restrict__ h, const int* __restrict__ adj,
    const float* __restrict__ edge, const float* __restrict__ fp,
    const float* __restrict__ Whd, const float* __restrict__ a1h,
    const float* __restrict__ a2h,
    const float* __restrict__ W_out, const float* __restrict__ a1o,
    const float* __restrict__ a2o,
    const float* __restrict__ fc1_w, const float* __restrict__ fc2_w,
    const float* __restrict__ q_w, const float* __restrict__ v_w,
    const float* __restrict__ o_w, const float* __restrict__ ffn1_w,
    const float* __restrict__ qb, const float* __restrict__ vb,
    ushort_t* __restrict__ hb, ushort_t* __restrict__ em,
    ushort_t* __restrict__ W2t, ushort_t* __restrict__ fpb,
    ushort_t* __restrict__ fc1t,
    ushort_t* __restrict__ Wot, ushort_t* __restrict__ fc2t,
    ushort_t* __restrict__ qwt, ushort_t* __restrict__ vwt,
    ushort_t* __restrict__ owt, ushort_t* __restrict__ f1t,
    float* __restrict__ wa1, float* __restrict__ wa2,
    ushort_t* __restrict__ wh12, float* __restrict__ qvb) {
  int bid = blockIdx.x;
  const int t = threadIdx.x;

  if (bid < 8) {  // wh12
    int hh = bid;
    if (t < 192) {
      float s1 = 0.f, s2 = 0.f;
      if (t < 133) {
        const float* wr = Whd + (size_t)(hh * 133 + t) * 64;
        const float* a1r = a1h + hh * 64;
        const float* a2r = a2h + hh * 64;
#pragma unroll 8
        for (int d = 0; d < 64; ++d) {
          float wv = wr[d];
          s1 += wv * a1r[d];
          s2 += wv * a2r[d];
        }
      }
      wh12[hh * 384 + t] = f2b(s1);
      wh12[hh * 384 + 192 + t] = f2b(s2);
    }
    return;
  }
  bid -= 8;
  if (bid < 128) {  // wa12
    int wv = t >> 6, lane = t & 63;
    int k = bid * 4 + wv;
    const float* wr = W_out + (size_t)k * 512;
    float p1 = 0.f, p2 = 0.f;
#pragma unroll
    for (int i = 0; i < 8; ++i) {
      float v = wr[lane + i * 64];
      p1 += v * a1o[lane + i * 64];
      p2 += v * a2o[lane + i * 64];
    }
#pragma unroll
    for (int off = 32; off; off >>= 1) {
      p1 += __shfl_down(p1, off);
      p2 += __shfl_down(p2, off);
    }
    if (lane == 0) { wa1[k] = p1; wa2[k] = p2; }
    return;
  }
  bid -= 128;
  if (bid < 2) {  // qvb
    int o = bid * 256 + t;
    qvb[o] = qb[o] + vb[o];
    return;
  }
  bid -= 2;
  if (bid < 96) {  // W2t
    int o = bid * 256 + t;
    if (o < 512 * 48) {
      int col = o / 48, c4 = (o - col * 48) * 4;
      int hh = col >> 6, d = col & 63;
      ushort4 v;
      v.x = (c4 + 0 < 133) ? f2b(Whd[(hh * 133 + c4 + 0) * 64 + d]) : (ushort_t)0;
      v.y = (c4 + 1 < 133) ? f2b(Whd[(hh * 133 + c4 + 1) * 64 + d]) : (ushort_t)0;
      v.z = (c4 + 2 < 133) ? f2b(Whd[(hh * 133 + c4 + 2) * 64 + d]) : (ushort_t)0;
      v.w = (c4 + 3 < 133) ? f2b(Whd[(hh * 133 + c4 + 3) * 64 + d]) : (ushort_t)0;
      *(ushort4*)&W2t[(size_t)col * KP1 + c4] = v;
    }
    return;
  }
  bid -= 96;
  if (bid < 768) {  // fpb
    int o = bid * 256 + t;
    int row = o / 384, c4 = (o - row * 384) * 4;
    const float* fr = fp + (size_t)row * 1489;
    ushort4 v;
    v.x = (c4 + 0 < 1489) ? f2b(fr[c4 + 0]) : (ushort_t)0;
    v.y = (c4 + 1 < 1489) ? f2b(fr[c4 + 1]) : (ushort_t)0;
    v.z = (c4 + 2 < 1489) ? f2b(fr[c4 + 2]) : (ushort_t)0;
    v.w = (c4 + 3 < 1489) ? f2b(fr[c4 + 3]) : (ushort_t)0;
    *(ushort4*)&fpb[(size_t)row * KPF + c4] = v;
    return;
  }
  bid -= 768;
  if (bid < 768) {  // fc1t (transpose K=1489 N=512 Kpad=1536)
    int o = bid * 256 + t;
    int col = o / 384, k4 = (o - col * 384) * 4;
    ushort4 v;
    v.x = (k4 + 0 < 1489) ? f2b(fc1_w[(size_t)(k4 + 0) * 512 + col]) : (ushort_t)0;
    v.y = (k4 + 1 < 1489) ? f2b(fc1_w[(size_t)(k4 + 1) * 512 + col]) : (ushort_t)0;
    v.z = (k4 + 2 < 1489) ? f2b(fc1_w[(size_t)(k4 + 2) * 512 + col]) : (ushort_t)0;
    v.w = (k4 + 3 < 1489) ? f2b(fc1_w[(size_t)(k4 + 3) * 512 + col]) : (ushort_t)0;
    *(ushort4*)&fc1t[(size_t)col * KPF + k4] = v;
    return;
  }
  bid -= 768;
  if (bid < 1536) {  // 6x 512x512 transposes
    int y = bid >> 8;
    int o = (bid & 255) * 256 + t;
    const float* W = y == 0 ? W_out : y == 1 ? fc2_w : y == 2 ? q_w
                   : y == 3 ? v_w : y == 4 ? o_w : ffn1_w;
    ushort_t* Wt = y == 0 ? Wot : y == 1 ? fc2t : y == 2 ? qwt
                 : y == 3 ? vwt : y == 4 ? owt : f1t;
    int col = o >> 7, k4 = (o & 127) * 4;
    ushort4 v;
    v.x = f2b(W[(size_t)(k4 + 0) * 512 + col]);
    v.y = f2b(W[(size_t)(k4 + 1) * 512 + col]);
    v.z = f2b(W[(size_t)(k4 + 2) * 512 + col]);
    v.w = f2b(W[(size_t)(k4 + 3) * 512 + col]);
    *(ushort4*)&Wt[(size_t)col * 512 + k4] = v;
    return;
  }
  bid -= 1536;
  if (bid < 12288) {  // hb
    int o = bid * 256 + t;
    int row = o / 48, c4 = (o - row * 48) * 4;
    const float* hr = h + (size_t)row * 133;
    ushort4 v;
    v.x = (c4 + 0 < 133) ? f2b(hr[c4 + 0]) : (ushort_t)0;
    v.y = (c4 + 1 < 133) ? f2b(hr[c4 + 1]) : (ushort_t)0;
    v.z = (c4 + 2 < 133) ? f2b(hr[c4 + 2]) : (ushort_t)0;
    v.w = (c4 + 3 < 133) ? f2b(hr[c4 + 3]) : (ushort_t)0;
    *(ushort4*)&hb[(size_t)row * KP1 + c4] = v;
    return;
  }
  bid -= 12288;
  {  // em
    size_t o = ((size_t)bid * 256 + t) * 4;
    float4 e = *(const float4*)&edge[o];
    int4 a = *(const int4*)&adj[o];
    ushort4 v;
    v.x = a.x > 0 ? f2b(e.x) : (ushort_t)MINF_BF16;
    v.y = a.y > 0 ? f2b(e.y) : (ushort_t)MINF_BF16;
    v.z = a.z > 0 ? f2b(e.z) : (ushort_t)MINF_BF16;
    v.w = a.w > 0 ? f2b(e.w) : (ushort_t)MINF_BF16;
    *(ushort4*)&em[o] = v;
  }
}

// ---------------------------------------------------------------------------
// att2t: t12x + att2 fused. 1 block/graph. Phase 1: t1/t2 rows (2 thr/row,
// wa staged in LDS). Phase 2: softmax -> aw bf16 + sinv.
__global__ __launch_bounds__(256) void att2t(
    const ushort_t* __restrict__ xb, const ushort_t* __restrict__ em,
    const float* __restrict__ wa1, const float* __restrict__ wa2,
    const float* __restrict__ aeo,
    ushort_t* __restrict__ awg, float* __restrict__ sinvg, int base) {
  __shared__ float t1s[128], t2s[128];
  __shared__ float was1[512], was2[512];
  const int bl = blockIdx.x, bg = base + bl;
  const int t = threadIdx.x;
  was1[t] = wa1[t]; was1[t + 256] = wa1[t + 256];
  was2[t] = wa2[t]; was2[t + 256] = wa2[t + 256];
  __syncthreads();
  const int row = t >> 1, half = t & 1;
  {
    const ushort_t* xr = xb + (size_t)(bl * 128 + row) * 512 + half * 256;
    float p1 = 0.f, p2 = 0.f;
#pragma unroll 4
    for (int i = 0; i < 32; ++i) {
      uint4 u = *(const uint4*)&xr[i * 8];
      const unsigned uu[4] = {u.x, u.y, u.z, u.w};
#pragma unroll
      for (int pr = 0; pr < 4; ++pr) {
        float lo = __uint_as_float(uu[pr] << 16);
        float hi = __uint_as_float(uu[pr] & 0xffff0000u);
        int c = half * 256 + i * 8 + pr * 2;
        p1 = fmaf(lo, was1[c], p1); p1 = fmaf(hi, was1[c + 1], p1);
        p2 = fmaf(lo, was2[c], p2); p2 = fmaf(hi, was2[c + 1], p2);
      }
    }
    p1 += __shfl_xor(p1, 1);
    p2 += __shfl_xor(p2, 1);
    if (!half) { t1s[row] = p1 * LOG2E; t2s[row] = p2 * LOG2E; }
  }
  __syncthreads();
  const float ae2 = aeo[0] * LOG2E;
  const float rt1 = t1s[row];
  const ushort_t* emr = em + (size_t)bg * 16384 + row * 128 + half * 64;
  ushort_t* awr = awg + (size_t)bl * 16384 + row * 128 + half * 64;
  float s = 0.f;
#pragma unroll
  for (int v = 0; v < 8; ++v) {
    uint4 eu = *(const uint4*)&emr[v * 8];
    const unsigned uu[4] = {eu.x, eu.y, eu.z, eu.w};
    unsigned po[4];
#pragma unroll
    for (int pr = 0; pr < 4; ++pr) {
      float elo = __uint_as_float(uu[pr] << 16);
      float ehi = __uint_as_float(uu[pr] & 0xffff0000u);
      float e0 = fmaf(elo, ae2, rt1 + t2s[half * 64 + v * 8 + pr * 2]);
      float e1 = fmaf(ehi, ae2, rt1 + t2s[half * 64 + v * 8 + pr * 2 + 1]);
      e0 = fmaxf(e0, ALPHA_LK * e0);
      e1 = fmaxf(e1, ALPHA_LK * e1);
      float p0 = (elo != -INFINITY) ? fexp2(e0) : 0.f;
      float p1 = (ehi != -INFINITY) ? fexp2(e1) : 0.f;
      unsigned q = cvt_pk(p0, p1);
      po[pr] = q;
      s += __uint_as_float(q << 16) + __uint_as_float(q & 0xffff0000u);
    }
    *(uint4*)&awr[v * 8] = make_uint4(po[0], po[1], po[2], po[3]);
  }
  s += __shfl_xor(s, 1);
  if (!half) sinvg[(size_t)bl * 128 + row] = 1.f / fmaxf(s, 1e-30f);
}

// ---------------------------------------------------------------------------
// FUSED GAT layer 1. 1D grid 8*C blocks, XCD-aware decode:
// xcd=id&7, head=(id>>3)&7, graph=(id>>6)*8+xcd.
// s1/s2 computed by MFMA: extra B fragment with cols {wh1, wh2, 0...}.
__global__ __launch_bounds__(256) void fused_gat1(
    const ushort_t* __restrict__ hb, const ushort_t* __restrict__ W2t,
    const ushort_t* __restrict__ edgeM, const ushort_t* __restrict__ wh12g,
    const float* __restrict__ ae,
    ushort_t* __restrict__ x, int base) {
  __shared__ union {
    struct { ushort_t As[128][64]; ushort_t Bs[64][64]; } g;  // 24 KB
    ushort_t WS[64][136];                                     // 17.4 KB
  } u;
  __shared__ float ss1[128], ss2[128];
  __shared__ ushort_t wh12s[2][192];
  const int id = blockIdx.x;
  const int hh = (id >> 3) & 7;
  const int bl = ((id >> 6) << 3) | (id & 7);
  const int bg = base + bl;
  const int t = threadIdx.x;
  const int lane = t & 63, w = t >> 6;
  const int l16 = lane & 15, quad = lane >> 4;
  const int w8 = w * 8, sr8 = (t >> 3) & 7;
  const int csw = ((t & 7) ^ sr8) << 3;  // pre-swizzled source column

  if (t < 96)
    *(ushort4*)&(&wh12s[0][0])[t * 4] =
        *(const ushort4*)&wh12g[hh * 384 + t * 4];

  // ---- Phase A: GEMM via direct global->LDS staging; s1/s2 ride along ----
  const ushort_t* gA = hb + (size_t)(bl * 128 + w8 + sr8) * KP1 + csw;
  const ushort_t* gB = W2t + (size_t)(hh * 64 + w8 + sr8) * KP1 + csw;
  ffrag acc[2][4];
  ffrag acc_s[2];
#pragma unroll
  for (int mi = 0; mi < 2; ++mi) {
    acc_s[mi] = {0.f, 0.f, 0.f, 0.f};
#pragma unroll
    for (int ni = 0; ni < 4; ++ni) acc[mi][ni] = {0.f, 0.f, 0.f, 0.f};
  }
  for (int k0 = 0; k0 < KP1; k0 += 64) {
    __syncthreads();
#pragma unroll
    for (int p = 0; p < 4; ++p)
      gll16(gA + (size_t)(p * 32) * KP1 + k0, &u.g.As[p * 32 + w8][0]);
#pragma unroll
    for (int p = 0; p < 2; ++p)
      gll16(gB + (size_t)(p * 32) * KP1 + k0, &u.g.Bs[p * 32 + w8][0]);
    __syncthreads();
#pragma unroll
    for (int ks = 0; ks < 2; ++ks) {
      const int cs = ((ks * 4 + quad) ^ (l16 & 7)) << 3;  // swizzled read
      bfrag af[2], bf[4];
      bfrag bs = {0, 0, 0, 0, 0, 0, 0, 0};
      if (l16 < 2)
        bs = *(const bfrag*)&wh12s[l16][k0 + ks * 32 + quad * 8];
#pragma unroll
      for (int mi = 0; mi < 2; ++mi)
        af[mi] = *(const bfrag*)&u.g.As[w * 32 + mi * 16 + l16][cs];
#pragma unroll
      for (int ni = 0; ni < 4; ++ni)
        bf[ni] = *(const bfrag*)&u.g.Bs[ni * 16 + l16][cs];
#pragma unroll
      for (int mi = 0; mi < 2; ++mi) {
#pragma unroll
        for (int ni = 0; ni < 4; ++ni)
          acc[mi][ni] = __builtin_amdgcn_mfma_f32_16x16x32_bf16(
              af[mi], bf[ni], acc[mi][ni], 0, 0, 0);
        acc_s[mi] = __builtin_amdgcn_mfma_f32_16x16x32_bf16(
            af[mi], bs, acc_s[mi], 0, 0, 0);
      }
    }
  }
  __syncthreads();  // staging dead; LDS becomes WS

  // ---- Phase B: transpose-store to WS[d][node] (cvt_pk packed) ----
#pragma unroll
  for (int mi = 0; mi < 2; ++mi)
#pragma unroll
    for (int ni = 0; ni < 4; ++ni) {
      int col = ni * 16 + l16;
      int rowb = w * 32 + mi * 16 + quad * 4;
      uint2 pv;
      pv.x = cvt_pk(acc[mi][ni][0], acc[mi][ni][1]);
      pv.y = cvt_pk(acc[mi][ni][2], acc[mi][ni][3]);
      *(uint2*)&u.WS[col][rowb] = pv;
    }
  // s1/s2: D cols 0/1 of acc_s hold s1/s2 for rows quad*4+r of each mi tile
  if (l16 < 2) {
    float* sp = (l16 == 0) ? ss1 : ss2;
#pragma unroll
    for (int mi = 0; mi < 2; ++mi)
#pragma unroll
      for (int r = 0; r < 4; ++r)
        sp[w * 32 + mi * 16 + quad * 4 + r] = acc_s[mi][r] * LOG2E;
  }
  // edgeM hoist
  uint4 ereg[2][4];
  {
    const ushort_t* em = edgeM + (size_t)bg * 16384;
#pragma unroll
    for (int mi = 0; mi < 2; ++mi) {
      int row = w * 32 + mi * 16 + l16;
#pragma unroll
      for (int ks = 0; ks < 4; ++ks)
        ereg[mi][ks] = *(const uint4*)&em[row * 128 + ks * 32 + quad * 8];
    }
  }
  __syncthreads();

  // ---- Phase C: register-resident attention (exp2 domain) ----
  const float aeh2 = ae[hh] * LOG2E;
  float rs1[2];
  rs1[0] = ss1[w * 32 + l16];
  rs1[1] = ss1[w * 32 + 16 + l16];
  uint4 aw[2][4];
#pragma unroll
  for (int mi = 0; mi < 2; ++mi) {
#pragma unroll
    for (int ks = 0; ks < 4; ++ks) {
      float s2v[8];
      *(float4*)&s2v[0] = *(const float4*)&ss2[ks * 32 + quad * 8];
      *(float4*)&s2v[4] = *(const float4*)&ss2[ks * 32 + quad * 8 + 4];
      const unsigned uu[4] = {ereg[mi][ks].x, ereg[mi][ks].y,
                              ereg[mi][ks].z, ereg[mi][ks].w};
      unsigned po[4];
#pragma unroll
      for (int pr = 0; pr < 4; ++pr) {
        float elo = __uint_as_float(uu[pr] << 16);
        float ehi = __uint_as_float(uu[pr] & 0xffff0000u);
        float e0 = fmaf(elo, aeh2, rs1[mi] + s2v[pr * 2]);
        float e1 = fmaf(ehi, aeh2, rs1[mi] + s2v[pr * 2 + 1]);
        e0 = fmaxf(e0, ALPHA_LK * e0);
        e1 = fmaxf(e1, ALPHA_LK * e1);
        float p0 = (elo != -INFINITY) ? fexp2(e0) : 0.f;
        float p1 = (ehi != -INFINITY) ? fexp2(e1) : 0.f;
        po[pr] = cvt_pk(p0, p1);
      }
      aw[mi][ks] = make_uint4(po[0], po[1], po[2], po[3]);
    }
  }

  // ones B-fragment: row sums of rounded aw ride along in the PV MFMA
  bfrag bones;
#pragma unroll
  for (int i = 0; i < 8; ++i) bones[i] = (short)0x3F80;

  ffrag acc2[2][4];
  ffrag accs[2];
#pragma unroll
  for (int mi = 0; mi < 2; ++mi) {
    accs[mi] = {0.f, 0.f, 0.f, 0.f};
#pragma unroll
    for (int ni = 0; ni < 4; ++ni) acc2[mi][ni] = {0.f, 0.f, 0.f, 0.f};
  }
#pragma unroll
  for (int ks = 0; ks < 4; ++ks) {
    bfrag bfr[4];
#pragma unroll
    for (int ni = 0; ni < 4; ++ni)
      bfr[ni] = *(const bfrag*)&u.WS[ni * 16 + l16][ks * 32 + quad * 8];
#pragma unroll
    for (int mi = 0; mi < 2; ++mi) {
      bfrag afr;
      __builtin_memcpy(&afr, &aw[mi][ks], 16);
#pragma unroll
      for (int ni = 0; ni < 4; ++ni)
        acc2[mi][ni] = __builtin_amdgcn_mfma_f32_16x16x32_bf16(
            afr, bfr[ni], acc2[mi][ni], 0, 0, 0);
      accs[mi] = __builtin_amdgcn_mfma_f32_16x16x32_bf16(
          afr, bones, accs[mi], 0, 0, 0);
    }
  }
  // accs[mi][r] = rowsum for row (w*32+mi*16+quad*4+r), replicated over l16
  float sv[2][4];
#pragma unroll
  for (int mi = 0; mi < 2; ++mi)
#pragma unroll
    for (int r = 0; r < 4; ++r)
      sv[mi][r] = frcp(fmaxf(accs[mi][r], 1e-30f));

#pragma unroll
  for (int mi = 0; mi < 2; ++mi)
#pragma unroll
    for (int ni = 0; ni < 4; ++ni) {
      float e0 = elu1(acc2[mi][ni][0] * sv[mi][0]);
      float e1 = elu1(acc2[mi][ni][1] * sv[mi][1]);
      float e2 = elu1(acc2[mi][ni][2] * sv[mi][2]);
      float e3 = elu1(acc2[mi][ni][3] * sv[mi][3]);
      unsigned p01 = cvt_pk(e0, e1), p23 = cvt_pk(e2, e3);
      int rl = w * 32 + mi * 16 + quad * 4;
      size_t bo = (size_t)(bl * 128 + rl) * 512 + hh * 64 + ni * 16 + l16;
      x[bo] = (ushort_t)p01;
      x[bo + 512] = (ushort_t)(p01 >> 16);
      x[bo + 1024] = (ushort_t)p23;
      x[bo + 1536] = (ushort_t)(p23 >> 16);
    }
}

// ---------------------------------------------------------------------------
// FUSED GAT output layer. 1D grid 4*C blocks, XCD-aware decode:
// xcd=id&7, sp2=(id>>3)&3, graph=(id>>5)*8+xcd. Softmax precomputed (att2t).
__global__ __launch_bounds__(256) void fused_gat2(
    const ushort_t* __restrict__ xb, const ushort_t* __restrict__ Wot,
    const ushort_t* __restrict__ awg, const float* __restrict__ sinvg,
    ushort_t* __restrict__ gatb, int base) {
  __shared__ union {
    struct { ushort_t As[128][64]; ushort_t Bs[128][64]; } g;  // 32 KB
    ushort_t WS[128][136];                                     // 34.8 KB
  } u;
  __shared__ float ps[4][64];
  const int id = blockIdx.x;
  const int sp2 = (id >> 3) & 3;
  const int bl = ((id >> 5) << 3) | (id & 7);
  const int bg = base + bl;
  const int t = threadIdx.x;
  const int lane = t & 63, w = t >> 6;
  const int wm = w >> 1, wn = w & 1;
  const int l16 = lane & 15, quad = lane >> 4;
  const int w8 = w * 8, sr8 = (t >> 3) & 7;
  const int csw = ((t & 7) ^ sr8) << 3;  // pre-swizzled source column

  // ---- Phase A: Wx tile = xb @ Wot^T (K=512), direct global->LDS ----
  const ushort_t* gA = xb + (size_t)(bl * 128 + w8 + sr8) * 512 + csw;
  const ushort_t* gB = Wot + (size_t)(sp2 * 128 + w8 + sr8) * 512 + csw;
  ffrag acc[4][4];
#pragma unroll
  for (int mi = 0; mi < 4; ++mi)
#pragma unroll
    for (int ni = 0; ni < 4; ++ni) acc[mi][ni] = {0.f, 0.f, 0.f, 0.f};
  for (int k0 = 0; k0 < 512; k0 += 64) {
    __syncthreads();
#pragma unroll
    for (int p = 0; p < 4; ++p) {
      gll16(gA + (size_t)(p * 32) * 512 + k0, &u.g.As[p * 32 + w8][0]);
      gll16(gB + (size_t)(p * 32) * 512 + k0, &u.g.Bs[p * 32 + w8][0]);
    }
    __syncthreads();
#pragma unroll
    for (int ks = 0; ks < 2; ++ks) {
      const int cs = ((ks * 4 + quad) ^ (l16 & 7)) << 3;  // swizzled read
      bfrag af[4], bf[4];
#pragma unroll
      for (int i = 0; i < 4; ++i) {
        af[i] = *(const bfrag*)&u.g.As[wm * 64 + i * 16 + l16][cs];
        bf[i] = *(const bfrag*)&u.g.Bs[wn * 64 + i * 16 + l16][cs];
      }
#pragma unroll
      for (int mi = 0; mi < 4; ++mi)
#pragma unroll
        for (int ni = 0; ni < 4; ++ni)
          acc[mi][ni] = __builtin_amdgcn_mfma_f32_16x16x32_bf16(
              af[mi], bf[ni], acc[mi][ni], 0, 0, 0);
    }
  }
  __syncthreads();

  // ---- Phase B: transpose-store to WS[col][node] (cvt_pk packed) ----
#pragma unroll
  for (int mi = 0; mi < 4; ++mi)
#pragma unroll
    for (int ni = 0; ni < 4; ++ni) {
      int col = wn * 64 + ni * 16 + l16;
      int rowb = wm * 64 + mi * 16 + quad * 4;
      uint2 pv;
      pv.x = cvt_pk(acc[mi][ni][0], acc[mi][ni][1]);
      pv.y = cvt_pk(acc[mi][ni][2], acc[mi][ni][3]);
      *(uint2*)&u.WS[col][rowb] = pv;
    }
  __syncthreads();

  // ---- Phase C: load precomputed attention weights + row-sum inverses ----
  uint4 awf[2][4];
  float sv[2][4];
  {
    const ushort_t* ap = awg + (size_t)bl * 16384;
#pragma unroll
    for (int mi = 0; mi < 2; ++mi) {
      int row = w * 32 + mi * 16 + l16;
#pragma unroll
      for (int ks = 0; ks < 4; ++ks)
        awf[mi][ks] = *(const uint4*)&ap[row * 128 + ks * 32 + quad * 8];
      float si = sinvg[(size_t)bl * 128 + row];
#pragma unroll
      for (int r = 0; r < 4; ++r) sv[mi][r] = __shfl(si, quad * 4 + r);
    }
  }

  // two 64-col strips; mean over 128 rows per col
  for (int s0 = 0; s0 < 2; ++s0) {
    ffrag acc2[2][4];
#pragma unroll
    for (int mi = 0; mi < 2; ++mi)
#pragma unroll
      for (int ni = 0; ni < 4; ++ni) acc2[mi][ni] = {0.f, 0.f, 0.f, 0.f};
#pragma unroll
    for (int ks = 0; ks < 4; ++ks) {
      bfrag bfr[4];
#pragma unroll
      for (int ni = 0; ni < 4; ++ni)
        bfr[ni] = *(const bfrag*)&u.WS[s0 * 64 + ni * 16 + l16][ks * 32 + quad * 8];
#pragma unroll
      for (int mi = 0; mi < 2; ++mi) {
        bfrag afr;
        __builtin_memcpy(&afr, &awf[mi][ks], 16);
#pragma unroll
        for (int ni = 0; ni < 4; ++ni)
          acc2[mi][ni] = __builtin_amdgcn_mfma_f32_16x16x32_bf16(
              afr, bfr[ni], acc2[mi][ni], 0, 0, 0);
      }
    }
    __syncthreads();
#pragma unroll
    for (int ni = 0; ni < 4; ++ni) {
      float s = 0.f;
#pragma unroll
      for (int mi = 0; mi < 2; ++mi)
#pragma unroll
        for (int r = 0; r < 4; ++r) s += elu1(acc2[mi][ni][r] * sv[mi][r]);
      s += __shfl_xor(s, 16);
      s += __shfl_xor(s, 32);
      if (quad == 0) ps[w][ni * 16 + l16] = s;
    }
    __syncthreads();
    if (t < 64) {
      float s = ps[0][t] + ps[1][t] + ps[2][t] + ps[3][t];
      gatb[(size_t)bg * 512 + sp2 * 128 + s0 * 64 + t] = f2b(s * (1.f / 128.f));
    }
  }
}

// ---------------------------------------------------------------------------
// tail GEMM K-loop helper (direct global->LDS staging, swizzled)
__device__ __forceinline__ void tail_kloop(
    const ushort_t* __restrict__ A, const ushort_t* __restrict__ Bt,
    int K, int ld, ushort_t (*As)[64], ushort_t (*Bs)[64],
    ffrag (*acc)[4], int row0, int col0, int t) {
  const int lane = t & 63, w = t >> 6;
  const int wm = w >> 1, wn = w & 1;
  const int l16 = lane & 15, quad = lane >> 4;
  const int w8 = w * 8, sr8 = (t >> 3) & 7;
  const int csw = ((t & 7) ^ sr8) << 3;
  const ushort_t* gA = A + (size_t)(row0 + w8 + sr8) * ld + csw;
  const ushort_t* gB = Bt + (size_t)(col0 + w8 + sr8) * ld + csw;
  for (int k0 = 0; k0 < K; k0 += 64) {
    __syncthreads();
#pragma unroll
    for (int p = 0; p < 4; ++p) {
      gll16(gA + (size_t)(p * 32) * ld + k0, &As[p * 32 + w8][0]);
      gll16(gB + (size_t)(p * 32) * ld + k0, &Bs[p * 32 + w8][0]);
    }
    __syncthreads();
#pragma unroll
    for (int ks = 0; ks < 2; ++ks) {
      const int cs = ((ks * 4 + quad) ^ (l16 & 7)) << 3;
      bfrag af[4], bf[4];
#pragma unroll
      for (int i = 0; i < 4; ++i) {
        af[i] = *(const bfrag*)&As[wm * 64 + i * 16 + l16][cs];
        bf[i] = *(const bfrag*)&Bs[wn * 64 + i * 16 + l16][cs];
      }
#pragma unroll
      for (int mi = 0; mi < 4; ++mi)
#pragma unroll
        for (int ni = 0; ni < 4; ++ni)
          acc[mi][ni] = __builtin_amdgcn_mfma_f32_16x16x32_bf16(
              af[mi], bf[ni], acc[mi][ni], 0, 0, 0);
    }
  }
}

// C_bf16[512][512] = act(A1@Bt1^T (+ A2@Bt2^T) + bias). grid (4,4).
template <int DUAL, int RELU>
__global__ __launch_bounds__(256) void gemm_tail(
    const ushort_t* __restrict__ A1, const ushort_t* __restrict__ Bt1,
    int K1, int ld1,
    const ushort_t* __restrict__ A2, const ushort_t* __restrict__ Bt2,
    const float* __restrict__ bias, ushort_t* __restrict__ C) {
  __shared__ ushort_t As[128][64];
  __shared__ ushort_t Bs[128][64];
  const int t = threadIdx.x;
  const int lane = t & 63, w = t >> 6;
  const int wm = w >> 1, wn = w & 1;
  const int l16 = lane & 15, quad = lane >> 4;
  const int row0 = blockIdx.y * 128, col0 = blockIdx.x * 128;

  ffrag acc[4][4];
#pragma unroll
  for (int mi = 0; mi < 4; ++mi)
#pragma unroll
    for (int ni = 0; ni < 4; ++ni) acc[mi][ni] = {0.f, 0.f, 0.f, 0.f};

  tail_kloop(A1, Bt1, K1, ld1, As, Bs, acc, row0, col0, t);
  if (DUAL) tail_kloop(A2, Bt2, 512, 512, As, Bs, acc, row0, col0, t);

#pragma unroll
  for (int mi = 0; mi < 4; ++mi)
#pragma unroll
    for (int ni = 0; ni < 4; ++ni) {
      int col = col0 + wn * 64 + ni * 16 + l16;
      float bb = bias[col];
      float v0 = acc[mi][ni][0] + bb, v1 = acc[mi][ni][1] + bb;
      float v2 = acc[mi][ni][2] + bb, v3 = acc[mi][ni][3] + bb;
      if (RELU) {
        v0 = fmaxf(v0, 0.f); v1 = fmaxf(v1, 0.f);
        v2 = fmaxf(v2, 0.f); v3 = fmaxf(v3, 0.f);
      }
      unsigned p01 = cvt_pk(v0, v1), p23 = cvt_pk(v2, v3);
      int row = row0 + wm * 64 + mi * 16 + quad * 4;
      size_t o = (size_t)row * 512 + col;
      C[o] = (ushort_t)p01;
      C[o + 512] = (ushort_t)(p01 >> 16);
      C[o + 1024] = (ushort_t)p23;
      C[o + 1536] = (ushort_t)(p23 >> 16);
    }
}

// out[512][12] f32 = f5_bf16[512][512] @ W[512][12] + b. one wave per row.
__global__ __launch_bounds__(256) void ffn2_kernel(
    const ushort_t* __restrict__ f5, const float* __restrict__ W,
    const float* __restrict__ b, float* __restrict__ out) {
  int wv = threadIdx.x >> 6, lane = threadIdx.x & 63;
  int row = blockIdx.x * 4 + wv;
  const ushort_t* fr = f5 + (size_t)row * 512;
  float v[8];
  ushort4 u0 = *(const ushort4*)&fr[lane * 8];
  ushort4 u1 = *(const ushort4*)&fr[lane * 8 + 4];
  v[0] = b2f(u0.x); v[1] = b2f(u0.y); v[2] = b2f(u0.z); v[3] = b2f(u0.w);
  v[4] = b2f(u1.x); v[5] = b2f(u1.y); v[6] = b2f(u1.z); v[7] = b2f(u1.w);
#pragma unroll
  for (int j = 0; j < 12; ++j) {
    float s = 0.f;
#pragma unroll
    for (int i = 0; i < 8; ++i) s += v[i] * W[(size_t)(lane * 8 + i) * 12 + j];
#pragma unroll
    for (int off = 32; off; off >>= 1) s += __shfl_down(s, off);
    if (lane == 0) out[(size_t)row * 12 + j] = s + b[j];
  }
}

// ---------------------------------------------------------------------------
extern "C" void kernel_launch(void* const* d_in, const int* in_sizes, int n_in,
                              void* d_out, int out_size, void* d_ws, size_t ws_size,
                              hipStream_t stream) {
  const float* h        = (const float*)d_in[0];
  const int*   adj      = (const int*)d_in[1];
  const float* edge     = (const float*)d_in[2];
  const float* fp       = (const float*)d_in[3];
  const float* W_heads  = (const float*)d_in[4];
  const float* a1_heads = (const float*)d_in[5];
  const float* a2_heads = (const float*)d_in[6];
  const float* ae_heads = (const float*)d_in[7];
  const float* W_out  = (const float*)d_in[8];
  const float* a1_out = (const float*)d_in[9];
  const float* a2_out = (const float*)d_in[10];
  const float* ae_out = (const float*)d_in[11];
  const float* fc1_w = (const float*)d_in[12];
  const float* fc1_b = (const float*)d_in[13];
  const float* fc2_w = (const float*)d_in[14];
  const float* fc2_b = (const float*)d_in[15];
  const float* q_w = (const float*)d_in[16];
  const float* q_b = (const float*)d_in[17];
  // k_w/k_b (18,19) dead: softmax over size-1 axis == 1 => fused = q + v
  const float* v_w = (const float*)d_in[20];
  const float* v_b = (const float*)d_in[21];
  const float* o_w = (const float*)d_in[22];
  const float* o_b = (const float*)d_in[23];
  const float* ffn1_w = (const float*)d_in[24];
  const float* ffn1_b = (const float*)d_in[25];
  const float* ffn2_w = (const float*)d_in[26];
  const float* ffn2_b = (const float*)d_in[27];
  float* out = (float*)d_out;

  // ---- workspace carve ----
  const size_t hb_bytes = (size_t)65536 * KP1 * 2;
  const size_t em_bytes = (size_t)512 * 16384 * 2;
  const size_t tail_bytes =
      (size_t)512 * KPF * 2 * 2 + (size_t)512 * 512 * 2 * 12 + 2048;
  const size_t fixed_bytes = hb_bytes + em_bytes + (size_t)512 * KP1 * 2 +
                             (size_t)2 * 65536 * 4 + tail_bytes + 16384;
  // per-chunk: xb (C*128*512*2) + awg (C*128*128*2) + sinv (C*128*4)
  int C = 32;
  for (int cand = 512; cand >= 32; cand >>= 1) {
    size_t need = (size_t)cand * (131072 + 32768 + 512) + fixed_bytes;
    if (need <= ws_size) { C = cand; break; }
  }
  const int M = C * 128;
  (void)M;

  char* p = (char*)d_ws;
  ushort_t* xb  = (ushort_t*)p; p += (size_t)C * 65536 * 2;  // [M][512]
  ushort_t* awg = (ushort_t*)p; p += (size_t)C * 16384 * 2;  // [C][128][128]
  float* sinv   = (float*)p;    p += (size_t)C * 128 * 4;    // [C][128]
  ushort_t* hb  = (ushort_t*)p; p += hb_bytes;
  ushort_t* em  = (ushort_t*)p; p += em_bytes;
  ushort_t* W2t = (ushort_t*)p; p += (size_t)512 * KP1 * 2;
  ushort_t* wh12 = (ushort_t*)p; p += 8 * 384 * 2;           // [8][2][192]
  float* t_unused = (float*)p; p += 2 * 65536 * 4 - 8 * 384 * 2;
  (void)t_unused;
  ushort_t* fpb  = (ushort_t*)p; p += (size_t)512 * KPF * 2;
  ushort_t* fc1t = (ushort_t*)p; p += (size_t)512 * KPF * 2;
  ushort_t* Wot  = (ushort_t*)p; p += (size_t)512 * 512 * 2;
  ushort_t* fc2t = (ushort_t*)p; p += (size_t)512 * 512 * 2;
  ushort_t* qwt  = (ushort_t*)p; p += (size_t)512 * 512 * 2;
  ushort_t* vwt  = (ushort_t*)p; p += (size_t)512 * 512 * 2;
  ushort_t* owt  = (ushort_t*)p; p += (size_t)512 * 512 * 2;
  ushort_t* f1t  = (ushort_t*)p; p += (size_t)512 * 512 * 2;
  ushort_t* gatb = (ushort_t*)p; p += (size_t)512 * 512 * 2;
  ushort_t* fb1  = (ushort_t*)p; p += (size_t)512 * 512 * 2;
  ushort_t* fb2  = (ushort_t*)p; p += (size_t)512 * 512 * 2;
  ushort_t* fb3  = (ushort_t*)p; p += (size_t)512 * 512 * 2;
  ushort_t* fb4  = (ushort_t*)p; p += (size_t)512 * 512 * 2;
  ushort_t* fb5  = (ushort_t*)p; p += (size_t)512 * 512 * 2;
  float* qvb = (float*)p; p += 2048;
  float* wa1 = (float*)p; p += 2048;
  float* wa2 = (float*)p; p += 2048;

  // preamble: ONE launch
  prep_all<<<23786, 256, 0, stream>>>(
      h, adj, edge, fp, W_heads, a1_heads, a2_heads,
      W_out, a1_out, a2_out,
      fc1_w, fc2_w, q_w, v_w, o_w, ffn1_w, q_b, v_b,
      hb, em, W2t, fpb, fc1t, Wot, fc2t, qwt, vwt, owt, f1t,
      wa1, wa2, wh12, qvb);

  for (int base = 0; base < 512; base += C) {
    fused_gat1<<<8 * C, 256, 0, stream>>>(
        hb + (size_t)base * 128 * KP1, W2t, em, wh12, ae_heads, xb, base);
    att2t<<<C, 256, 0, stream>>>(xb, em, wa1, wa2, ae_out, awg, sinv, base);
    fused_gat2<<<4 * C, 256, 0, stream>>>(xb, Wot, awg, sinv, gatb, base);
  }

  // tail: FPN + fusion + FFN
  gemm_tail<0, 1><<<dim3(4, 4), 256, 0, stream>>>(
      fpb, fc1t, KPF, KPF, nullptr, nullptr, fc1_b, fb1);
  gemm_tail<0, 0><<<dim3(4, 4), 256, 0, stream>>>(
      fb1, fc2t, 512, 512, nullptr, nullptr, fc2_b, fb2);
  gemm_tail<1, 0><<<dim3(4, 4), 256, 0, stream>>>(
      gatb, qwt, 512, 512, fb2, vwt, qvb, fb3);          // q + v fused
  gemm_tail<0, 1><<<dim3(4, 4), 256, 0, stream>>>(
      fb3, owt, 512, 512, nullptr, nullptr, o_b, fb4);
  gemm_tail<0, 1><<<dim3(4, 4), 256, 0, stream>>>(
      fb4, f1t, 512, 512, nullptr, nullptr, ffn1_b, fb5);
  ffn2_kernel<<<128, 256, 0, stream>>>(fb5, ffn2_w, ffn2_b, out);
}